// Round 13
// baseline (576.905 us; speedup 1.0000x reference)
//
#include <hip/hip_runtime.h>
#include <hip/hip_cooperative_groups.h>
#include <hip/hip_bf16.h>

namespace cg = cooperative_groups;

#define IN_FEATS 768
#define PART_CHUNK 8192
#define SRC_BITS 17
#define SRC_MASK 0x1FFFF

typedef __attribute__((ext_vector_type(8))) short short8v;
typedef __attribute__((ext_vector_type(4))) float f32x4;

__device__ __forceinline__ unsigned short f2bf(float f) {
    union { float f; unsigned int u; } c; c.f = f;
    unsigned int r = (c.u + 0x7FFFu + ((c.u >> 16) & 1u)) >> 16;  // RNE
    return (unsigned short)r;
}
__device__ __forceinline__ float bflo(unsigned int v) {
    union { unsigned int u; float f; } c; c.u = v << 16; return c.f;
}
__device__ __forceinline__ float bfhi(unsigned int v) {
    union { unsigned int u; float f; } c; c.u = v & 0xFFFF0000u; return c.f;
}
__device__ __forceinline__ short8v pack8(float4 p, float4 q) {
    short8v r;
    r[0] = (short)f2bf(p.x); r[1] = (short)f2bf(p.y);
    r[2] = (short)f2bf(p.z); r[3] = (short)f2bf(p.w);
    r[4] = (short)f2bf(q.x); r[5] = (short)f2bf(q.y);
    r[6] = (short)f2bf(q.z); r[7] = (short)f2bf(q.w);
    return r;
}

struct MegaParams {
    const float* x;
    const float* Wn;
    const float* Ws;
    const float* b1;
    const float* Wn2;
    const float* Ws2;
    const float* b2;
    const int* src;
    const int* dst;
    unsigned short* hn1b;   // [2][N][16] bf16 halves
    float* hs1;             // [N,32]
    unsigned short* hn2b;   // [N,8]
    float* hs2;             // [N,8]
    int* rowstart;          // [N]
    int* rowcnt;            // [N]
    int* bcursor;           // [512]
    unsigned int* packed;   // [NB*CAP]
    int* edge_src;          // [NB*CAP]
    float* out;             // [N,8]
    int N, E, NB, CAP, nbPart, nbGemm;
};

// ---------------------------------------------------------------------------
// P1a: one 8192-edge partition chunk (r12 partition role, chunk-indexed).
// ---------------------------------------------------------------------------
__device__ __forceinline__ void partition_chunk(
    const MegaParams& p, int chunk, int tid, unsigned char* smem)
{
    int* hcnt  = (int*)smem;          // [512]
    int* hbase = hcnt + 512;          // [512]

    for (int i = tid; i < p.NB; i += 256) hcnt[i] = 0;
    __syncthreads();

    const int start = chunk * PART_CHUNK;
    const int end   = min(start + PART_CHUNK, p.E);
    const int vend  = start + ((end - start) & ~3);

    for (int i = start + tid * 4; i + 3 < end; i += 1024) {
        const int4 d4 = *(const int4*)&p.dst[i];
        atomicAdd(&hcnt[d4.x >> 8], 1);
        atomicAdd(&hcnt[d4.y >> 8], 1);
        atomicAdd(&hcnt[d4.z >> 8], 1);
        atomicAdd(&hcnt[d4.w >> 8], 1);
    }
    for (int i = vend + tid; i < end; i += 256)
        atomicAdd(&hcnt[p.dst[i] >> 8], 1);
    __syncthreads();

    for (int i = tid; i < p.NB; i += 256) {
        const int c = hcnt[i];
        hbase[i] = c ? atomicAdd(&p.bcursor[i], c) : 0;
        hcnt[i] = 0;
    }
    __syncthreads();

    for (int i = start + tid * 4; i + 3 < end; i += 1024) {
        const int4 d4 = *(const int4*)&p.dst[i];
        const int4 s4 = *(const int4*)&p.src[i];
        {
            const int b = d4.x >> 8;
            const int q = hbase[b] + atomicAdd(&hcnt[b], 1);
            if (q < (b + 1) * p.CAP) p.packed[q] = ((unsigned int)(d4.x & 255) << SRC_BITS) | (unsigned int)s4.x;
        }
        {
            const int b = d4.y >> 8;
            const int q = hbase[b] + atomicAdd(&hcnt[b], 1);
            if (q < (b + 1) * p.CAP) p.packed[q] = ((unsigned int)(d4.y & 255) << SRC_BITS) | (unsigned int)s4.y;
        }
        {
            const int b = d4.z >> 8;
            const int q = hbase[b] + atomicAdd(&hcnt[b], 1);
            if (q < (b + 1) * p.CAP) p.packed[q] = ((unsigned int)(d4.z & 255) << SRC_BITS) | (unsigned int)s4.z;
        }
        {
            const int b = d4.w >> 8;
            const int q = hbase[b] + atomicAdd(&hcnt[b], 1);
            if (q < (b + 1) * p.CAP) p.packed[q] = ((unsigned int)(d4.w & 255) << SRC_BITS) | (unsigned int)s4.w;
        }
    }
    for (int i = vend + tid; i < end; i += 256) {
        const int d = p.dst[i];
        const int b = d >> 8;
        const int q = hbase[b] + atomicAdd(&hcnt[b], 1);
        if (q < (b + 1) * p.CAP) p.packed[q] = ((unsigned int)(d & 255) << SRC_BITS) | (unsigned int)p.src[i];
    }
}

// ---------------------------------------------------------------------------
// P1b: one 64-row GEMM tile (r12 gemm role v2: [2][64][72], 1 barrier/step).
// ---------------------------------------------------------------------------
__device__ __forceinline__ void gemm_tile(
    const MegaParams& p, int t, int tid, unsigned char* smem)
{
    unsigned short* AsB = (unsigned short*)smem;      // [2][64][72]
    unsigned short* BsB = AsB + 2 * 64 * 72;          // [2][64][72]

    const int lrow = tid >> 2;
    const int lk16 = (tid & 3) * 16;
    const int row0 = t * 64;

    const int  grow   = row0 + lrow;
    const bool rvalid = (grow < p.N);
    const float* xrow = p.x + (size_t)(rvalid ? grow : (p.N - 1)) * IN_FEATS;
    const float* wrow = (lrow < 32) ? (p.Wn + (size_t)lrow * IN_FEATS)
                                    : (p.Ws + (size_t)(lrow - 32) * IN_FEATS);

    const int w    = tid >> 6;
    const int l    = tid & 63;
    const int lr16 = l & 15;
    const int lk   = (l >> 4) * 8;

    f32x4 acc[4];
#pragma unroll
    for (int ct = 0; ct < 4; ++ct) acc[ct] = (f32x4){0.f, 0.f, 0.f, 0.f};

    float4 a0, a1, a2, a3, w0, w1, w2, w3;
    a0 = *(const float4*)(xrow + lk16 + 0);
    a1 = *(const float4*)(xrow + lk16 + 4);
    a2 = *(const float4*)(xrow + lk16 + 8);
    a3 = *(const float4*)(xrow + lk16 + 12);
    w0 = *(const float4*)(wrow + lk16 + 0);
    w1 = *(const float4*)(wrow + lk16 + 4);
    w2 = *(const float4*)(wrow + lk16 + 8);
    w3 = *(const float4*)(wrow + lk16 + 12);

    const int NSTEP = IN_FEATS / 64;    // 12
    for (int step = 0; step < NSTEP; ++step) {
        const int buf = step & 1;
        unsigned short* as = AsB + (buf * 64 + lrow) * 72;
        unsigned short* bs = BsB + (buf * 64 + lrow) * 72;
        *(short8v*)(as + lk16)     = pack8(a0, a1);
        *(short8v*)(as + lk16 + 8) = pack8(a2, a3);
        *(short8v*)(bs + lk16)     = pack8(w0, w1);
        *(short8v*)(bs + lk16 + 8) = pack8(w2, w3);
        __syncthreads();

        if (step + 1 < NSTEP) {
            const int k0 = (step + 1) * 64;
            a0 = *(const float4*)(xrow + k0 + lk16 + 0);
            a1 = *(const float4*)(xrow + k0 + lk16 + 4);
            a2 = *(const float4*)(xrow + k0 + lk16 + 8);
            a3 = *(const float4*)(xrow + k0 + lk16 + 12);
            w0 = *(const float4*)(wrow + k0 + lk16 + 0);
            w1 = *(const float4*)(wrow + k0 + lk16 + 4);
            w2 = *(const float4*)(wrow + k0 + lk16 + 8);
            w3 = *(const float4*)(wrow + k0 + lk16 + 12);
        }

        const unsigned short* ar = AsB + (buf * 64 + w * 16 + lr16) * 72;
        short8v af0 = *(const short8v*)(ar + lk);
        short8v af1 = *(const short8v*)(ar + lk + 32);
#pragma unroll
        for (int ct = 0; ct < 4; ++ct) {
            const unsigned short* br = BsB + (buf * 64 + ct * 16 + lr16) * 72;
            short8v bf0 = *(const short8v*)(br + lk);
            acc[ct] = __builtin_amdgcn_mfma_f32_16x16x32_bf16(af0, bf0, acc[ct], 0, 0, 0);
        }
#pragma unroll
        for (int ct = 0; ct < 4; ++ct) {
            const unsigned short* br = BsB + (buf * 64 + ct * 16 + lr16) * 72;
            short8v bf1 = *(const short8v*)(br + lk + 32);
            acc[ct] = __builtin_amdgcn_mfma_f32_16x16x32_bf16(af1, bf1, acc[ct], 0, 0, 0);
        }
    }

    const int rbase = row0 + w * 16 + (l >> 4) * 4;
#pragma unroll
    for (int ct = 0; ct < 4; ++ct) {
        const int ncol = ct * 16 + lr16;
        if (ncol < 32) {
            const int half = ncol >> 4;
            const int c16  = ncol & 15;
            unsigned short* hd = p.hn1b + (size_t)half * p.N * 16;
#pragma unroll
            for (int j = 0; j < 4; ++j) {
                const int r = rbase + j;
                if (r < p.N) hd[(size_t)r * 16 + c16] = f2bf(acc[ct][j]);
            }
        } else {
            const int c = ncol - 32;
            const float bias = p.b1[c];
#pragma unroll
            for (int j = 0; j < 4; ++j) {
                const int r = rbase + j;
                if (r < p.N) p.hs1[(size_t)r * 32 + c] = acc[ct][j] + bias;
            }
        }
    }
}

// ---------------------------------------------------------------------------
// P2: per-bucket CSR finalize (256-thread version of r12's kernel).
// ---------------------------------------------------------------------------
__device__ __forceinline__ void finalize_bucket(
    const MegaParams& p, int b, int tid, unsigned char* smem)
{
    int* cnt   = (int*)smem;          // [256]
    int* sdata = cnt + 256;           // [256]
    int* cur   = sdata + 256;         // [256]

    const int base = b * p.CAP;
    const int endp = min(p.bcursor[b], base + p.CAP);

    cnt[tid] = 0;
    __syncthreads();
    for (int i = base + tid; i < endp; i += 256)
        atomicAdd(&cnt[p.packed[i] >> SRC_BITS], 1);
    __syncthreads();

    sdata[tid] = cnt[tid];
    __syncthreads();
    for (int off = 1; off < 256; off <<= 1) {
        const int add = (tid >= off) ? sdata[tid - off] : 0;
        __syncthreads();
        sdata[tid] += add;
        __syncthreads();
    }
    const int excl = (tid > 0) ? sdata[tid - 1] : 0;
    const int n = (b << 8) + tid;
    if (n < p.N) {
        p.rowstart[n] = base + excl;
        p.rowcnt[n]   = cnt[tid];
    }
    cur[tid] = base + excl;
    __syncthreads();

    for (int i = base + tid; i < endp; i += 256) {
        const unsigned int v = p.packed[i];
        const int pos = atomicAdd(&cur[v >> SRC_BITS], 1);
        p.edge_src[pos] = (int)(v & SRC_MASK);
    }
}

// ---------------------------------------------------------------------------
// Mega-kernel: all phases in one cooperative launch (kills ~12-16us/launch
// graph-node overhead measured across r5..r12 ledgers).
// ---------------------------------------------------------------------------
__global__ __launch_bounds__(256, 4) void mega_kernel(MegaParams p)
{
    __shared__ __align__(16) unsigned char smem[36864];
    cg::grid_group gg = cg::this_grid();
    const int tid  = threadIdx.x;
    const int bid  = blockIdx.x;
    const int nblk = gridDim.x;

    // ---- P0: init bucket cursors ----
    for (int i = bid * 256 + tid; i < p.NB; i += nblk * 256)
        p.bcursor[i] = i * p.CAP;
    gg.sync();

    // ---- P1: edge partition (items 0..nbPart) || layer-1 GEMM tiles ----
    const int totalP1 = p.nbPart + p.nbGemm;
    for (int item = bid; item < totalP1; item += nblk) {
        if (item < p.nbPart) partition_chunk(p, item, tid, smem);
        else                 gemm_tile(p, item - p.nbPart, tid, smem);
        __syncthreads();    // LDS reuse between items
    }
    gg.sync();

    // ---- P2: per-bucket CSR finalize ----
    for (int b = bid; b < p.NB; b += nblk) {
        finalize_bucket(p, b, tid, smem);
        __syncthreads();
    }
    gg.sync();

    // ---- P3: agg1 (two L2-resident half passes) + layer-2 linear ----
    {
        float* w2  = (float*)smem;          // [16][33]
        float* bb  = w2 + 16 * 33;          // [8]
        float* hsm = bb + 8;                // [32][33]

        w2[(tid >> 5) * 33 + (tid & 31)]       = p.Wn2[tid];
        w2[(8 + (tid >> 5)) * 33 + (tid & 31)] = p.Ws2[tid];
        if (tid < 8) bb[tid] = p.b2[tid];
        __syncthreads();

        const int g  = tid >> 3;     // node slot 0..31
        const int ln = tid & 7;      // pair lane 0..7
        const int ngroups = (p.N + 31) / 32;

        for (int gi = bid; gi < ngroups; gi += nblk) {
            const int n = gi * 32 + g;
            int rs = 0, degi = 0;
            if (n < p.N) { rs = p.rowstart[n]; degi = p.rowcnt[n]; }
            const float inv = 1.0f / fmaxf((float)degi, 1.0f);
            const int re = rs + degi;

#pragma unroll
            for (int h = 0; h < 2; ++h) {
                const unsigned int* tab = (const unsigned int*)p.hn1b + (size_t)h * p.N * 8;
                float sx = 0.f, sy = 0.f;
                if (n < p.N) {
                    int e = rs;
                    for (; e + 4 <= re; e += 4) {
                        const int s0 = p.edge_src[e + 0];
                        const int s1 = p.edge_src[e + 1];
                        const int s2 = p.edge_src[e + 2];
                        const int s3 = p.edge_src[e + 3];
                        const unsigned int v0 = tab[(size_t)s0 * 8 + ln];
                        const unsigned int v1 = tab[(size_t)s1 * 8 + ln];
                        const unsigned int v2 = tab[(size_t)s2 * 8 + ln];
                        const unsigned int v3 = tab[(size_t)s3 * 8 + ln];
                        sx += (bflo(v0) + bflo(v1)) + (bflo(v2) + bflo(v3));
                        sy += (bfhi(v0) + bfhi(v1)) + (bfhi(v2) + bfhi(v3));
                    }
                    for (; e < re; ++e) {
                        const unsigned int v = tab[(size_t)p.edge_src[e] * 8 + ln];
                        sx += bflo(v); sy += bfhi(v);
                    }
                    const int f = h * 16 + 2 * ln;
                    const float2 hsv = *(const float2*)(p.hs1 + (size_t)n * 32 + f);
                    hsm[g * 33 + f + 0] = fmaxf(hsv.x + sx * inv, 0.0f);
                    hsm[g * 33 + f + 1] = fmaxf(hsv.y + sy * inv, 0.0f);
                }
            }
            __syncthreads();

            if (n < p.N) {
                const float* hv = hsm + g * 33;
#pragma unroll
                for (int o2 = 0; o2 < 2; ++o2) {
                    const int o = o2 * 8 + ln;
                    const float* wr = w2 + o * 33;
                    float acc = 0.0f;
#pragma unroll
                    for (int k = 0; k < 32; ++k) acc += wr[k] * hv[k];
                    if (o < 8) p.hn2b[(size_t)n * 8 + o] = f2bf(acc);
                    else       p.hs2[(size_t)n * 8 + (o - 8)] = acc + bb[o - 8];
                }
            }
            __syncthreads();    // hsm reuse next group
        }
    }
    gg.sync();

    // ---- P4: agg2 + final combine -> out ----
    {
        const int g    = tid >> 4;
        const int ln   = tid & 15;
        const int slot = ln >> 2;
        const int q    = ln & 3;
        const unsigned int* hn2u = (const unsigned int*)p.hn2b;
        const int ng2 = (p.N + 15) / 16;

        for (int gi = bid; gi < ng2; gi += nblk) {
            const int n = gi * 16 + g;
            float sx = 0.f, sy = 0.f;
            int degi = 0;
            if (n < p.N) {
                const int rs = p.rowstart[n];
                degi = p.rowcnt[n];
                const int re = rs + degi;
                for (int e = rs + slot; e < re; e += 4) {
                    const unsigned int v = hn2u[(size_t)p.edge_src[e] * 4 + q];
                    sx += bflo(v); sy += bfhi(v);
                }
            }
            sx += __shfl_xor(sx, 4, 64);  sy += __shfl_xor(sy, 4, 64);
            sx += __shfl_xor(sx, 8, 64);  sy += __shfl_xor(sy, 8, 64);

            if (n < p.N && slot == 0) {
                const float inv = 1.0f / fmaxf((float)degi, 1.0f);
                const float2 s = *(const float2*)(p.hs2 + (size_t)n * 8 + 2 * q);
                float2 o;
                o.x = s.x + sx * inv;
                o.y = s.y + sy * inv;
                *(float2*)(p.out + (size_t)n * 8 + 2 * q) = o;
            }
        }
    }
}

extern "C" void kernel_launch(void* const* d_in, const int* in_sizes, int n_in,
                              void* d_out, int out_size, void* d_ws, size_t ws_size,
                              hipStream_t stream)
{
    const float* feats = (const float*)d_in[0];
    const int*   src   = (const int*)d_in[1];
    const int*   dst   = (const int*)d_in[2];
    const float* Ws1   = (const float*)d_in[3];
    const float* Wn1   = (const float*)d_in[4];
    const float* b1    = (const float*)d_in[5];
    const float* Ws2   = (const float*)d_in[6];
    const float* Wn2   = (const float*)d_in[7];
    const float* b2    = (const float*)d_in[8];
    float* out = (float*)d_out;

    const int N  = in_sizes[0] / IN_FEATS;   // 100000
    const int E  = in_sizes[1];              // 3200000
    const int NB = (N + 255) >> 8;           // 391
    const int CAP = (int)((((2LL * E) / NB) + 255) & ~255LL);   // 16384

    // Workspace layout (same as round 12)
    char* ws = (char*)d_ws;
    const size_t N32 = (size_t)N * 32;
    const size_t N8  = (size_t)N * 8;
    unsigned short* hn1b = (unsigned short*)ws;            // [2][N][16] bf16
    ws += ((N32 * 2 + 255) / 256) * 256;
    float* hs1 = (float*)ws;                               // [N,32] f32
    ws += ((N32 * 4 + 255) / 256) * 256;
    unsigned short* hn2b = (unsigned short*)ws;            // [N,8] bf16
    ws += ((N8 * 2 + 255) / 256) * 256;
    float* hs2 = (float*)ws;                               // [N,8] f32
    ws += ((N8 * 4 + 255) / 256) * 256;
    int* rowstart = (int*)ws;                              // [N]
    ws += (((size_t)N * 4 + 255) / 256) * 256;
    int* rowcnt = (int*)ws;                                // [N]
    ws += (((size_t)N * 4 + 255) / 256) * 256;
    int* bcursor = (int*)ws;                               // [512]
    ws += 512 * 4;
    unsigned int* packed = (unsigned int*)ws;              // [NB*CAP]
    ws += (((size_t)NB * CAP * 4 + 255) / 256) * 256;
    int* edge_src = (int*)ws;                              // [NB*CAP]

    MegaParams mp;
    mp.x = feats; mp.Wn = Wn1; mp.Ws = Ws1; mp.b1 = b1;
    mp.Wn2 = Wn2; mp.Ws2 = Ws2; mp.b2 = b2;
    mp.src = src; mp.dst = dst;
    mp.hn1b = hn1b; mp.hs1 = hs1; mp.hn2b = hn2b; mp.hs2 = hs2;
    mp.rowstart = rowstart; mp.rowcnt = rowcnt;
    mp.bcursor = bcursor; mp.packed = packed; mp.edge_src = edge_src;
    mp.out = out;
    mp.N = N; mp.E = E; mp.NB = NB; mp.CAP = CAP;
    mp.nbPart = (E + PART_CHUNK - 1) / PART_CHUNK;   // 391
    mp.nbGemm = (N + 63) / 64;                       // 1563

    // Cooperative grid: blocks/CU from occupancy query (expect 4 at 36KB LDS,
    // launch_bounds(256,4)); 256 CUs on MI355X. Grid-stride loops tolerate
    // any grid size; cooperative launch requires grid <= co-resident capacity.
    int maxPerCU = 0;
    if (hipOccupancyMaxActiveBlocksPerMultiprocessor(&maxPerCU, mega_kernel,
                                                     256, 0) != hipSuccess ||
        maxPerCU < 1)
        maxPerCU = 1;
    if (maxPerCU > 4) maxPerCU = 4;
    const int gridBlocks = maxPerCU * 256;

    void* args[] = { (void*)&mp };
    hipLaunchCooperativeKernel(mega_kernel, dim3(gridBlocks), dim3(256),
                               args, 0, stream);
}

// Round 14
// 254.781 us; speedup vs baseline: 2.2643x; 2.2643x over previous
//
#include <hip/hip_runtime.h>
#include <hip/hip_bf16.h>

#define IN_FEATS 768
#define PART_CHUNK 8192
#define SRC_BITS 17
#define SRC_MASK 0x1FFFF

typedef __attribute__((ext_vector_type(8))) short short8v;
typedef __attribute__((ext_vector_type(4))) float f32x4;

__device__ __forceinline__ unsigned short f2bf(float f) {
    union { float f; unsigned int u; } c; c.f = f;
    unsigned int r = (c.u + 0x7FFFu + ((c.u >> 16) & 1u)) >> 16;  // RNE
    return (unsigned short)r;
}
__device__ __forceinline__ float bflo(unsigned int v) {
    union { unsigned int u; float f; } c; c.u = v << 16; return c.f;
}
__device__ __forceinline__ float bfhi(unsigned int v) {
    union { unsigned int u; float f; } c; c.u = v & 0xFFFF0000u; return c.f;
}
__device__ __forceinline__ short8v pack8(float4 p, float4 q) {
    short8v r;
    r[0] = (short)f2bf(p.x); r[1] = (short)f2bf(p.y);
    r[2] = (short)f2bf(p.z); r[3] = (short)f2bf(p.w);
    r[4] = (short)f2bf(q.x); r[5] = (short)f2bf(q.y);
    r[6] = (short)f2bf(q.z); r[7] = (short)f2bf(q.w);
    return r;
}

// ---------------------------------------------------------------------------
// init cursor: bcursor[b] = b*CAP
// ---------------------------------------------------------------------------
__global__ __launch_bounds__(512) void init_cursor_kernel(
    int* __restrict__ bcursor, int NB, int CAP)
{
    const int t = threadIdx.x;
    if (t < NB) bcursor[t] = t * CAP;
}

// ---------------------------------------------------------------------------
// FUSED: blocks [0,nbPart) = edge partition; rest = layer-1 bf16-MFMA GEMM
// (r12 verbatim — measured best so far; cooperative mega-kernel in r13 lost
// ~650us to grid-sync cost on 8 XCDs and was reverted).
// ---------------------------------------------------------------------------
__global__ __launch_bounds__(256) void gemm_part_kernel(
    const float* __restrict__ x,
    const float* __restrict__ Wn,
    const float* __restrict__ Ws,
    const float* __restrict__ b1,
    unsigned short* __restrict__ hn1b,   // [2][N][16] bf16 halves
    float* __restrict__ hs1,             // [N,32]
    int N,
    const int* __restrict__ src, const int* __restrict__ dst,
    int* __restrict__ bcursor, unsigned int* __restrict__ packed,
    int NB, int E, int CAP, int nbPart)
{
    __shared__ __align__(16) unsigned char smem[36864];
    const int tid = threadIdx.x;

    if ((int)blockIdx.x < nbPart) {
        // ================= partition role =================
        int* hcnt  = (int*)smem;         // [512]
        int* hbase = hcnt + 512;         // [512]

        for (int i = tid; i < NB; i += 256) hcnt[i] = 0;
        __syncthreads();

        const int start = blockIdx.x * PART_CHUNK;
        const int end   = min(start + PART_CHUNK, E);
        const int vend  = start + ((end - start) & ~3);

        for (int i = start + tid * 4; i + 3 < end; i += 1024) {
            const int4 d4 = *(const int4*)&dst[i];
            atomicAdd(&hcnt[d4.x >> 8], 1);
            atomicAdd(&hcnt[d4.y >> 8], 1);
            atomicAdd(&hcnt[d4.z >> 8], 1);
            atomicAdd(&hcnt[d4.w >> 8], 1);
        }
        for (int i = vend + tid; i < end; i += 256)
            atomicAdd(&hcnt[dst[i] >> 8], 1);
        __syncthreads();

        for (int i = tid; i < NB; i += 256) {
            const int c = hcnt[i];
            hbase[i] = c ? atomicAdd(&bcursor[i], c) : 0;
            hcnt[i] = 0;
        }
        __syncthreads();

        for (int i = start + tid * 4; i + 3 < end; i += 1024) {
            const int4 d4 = *(const int4*)&dst[i];
            const int4 s4 = *(const int4*)&src[i];
            {
                const int b = d4.x >> 8;
                const int p = hbase[b] + atomicAdd(&hcnt[b], 1);
                if (p < (b + 1) * CAP) packed[p] = ((unsigned int)(d4.x & 255) << SRC_BITS) | (unsigned int)s4.x;
            }
            {
                const int b = d4.y >> 8;
                const int p = hbase[b] + atomicAdd(&hcnt[b], 1);
                if (p < (b + 1) * CAP) packed[p] = ((unsigned int)(d4.y & 255) << SRC_BITS) | (unsigned int)s4.y;
            }
            {
                const int b = d4.z >> 8;
                const int p = hbase[b] + atomicAdd(&hcnt[b], 1);
                if (p < (b + 1) * CAP) packed[p] = ((unsigned int)(d4.z & 255) << SRC_BITS) | (unsigned int)s4.z;
            }
            {
                const int b = d4.w >> 8;
                const int p = hbase[b] + atomicAdd(&hcnt[b], 1);
                if (p < (b + 1) * CAP) packed[p] = ((unsigned int)(d4.w & 255) << SRC_BITS) | (unsigned int)s4.w;
            }
        }
        for (int i = vend + tid; i < end; i += 256) {
            const int d = dst[i];
            const int b = d >> 8;
            const int p = hbase[b] + atomicAdd(&hcnt[b], 1);
            if (p < (b + 1) * CAP) packed[p] = ((unsigned int)(d & 255) << SRC_BITS) | (unsigned int)src[i];
        }
        return;
    }

    // ================= gemm role (v2: [2][64][72], one barrier/step) =======
    unsigned short* AsB = (unsigned short*)smem;          // [2][64][72]
    unsigned short* BsB = AsB + 2 * 64 * 72;              // [2][64][72]
#define AS(b, r) (AsB + ((b) * 64 + (r)) * 72)
#define BS(b, r) (BsB + ((b) * 64 + (r)) * 72)

    const int lrow = tid >> 2;
    const int lk16 = (tid & 3) * 16;
    const int row0 = ((int)blockIdx.x - nbPart) * 64;

    const int  grow   = row0 + lrow;
    const bool rvalid = (grow < N);
    const float* xrow = x + (size_t)(rvalid ? grow : (N - 1)) * IN_FEATS;
    const float* wrow = (lrow < 32) ? (Wn + (size_t)lrow * IN_FEATS)
                                    : (Ws + (size_t)(lrow - 32) * IN_FEATS);

    const int w    = tid >> 6;
    const int l    = tid & 63;
    const int lr16 = l & 15;
    const int lk   = (l >> 4) * 8;

    f32x4 acc[4];
#pragma unroll
    for (int ct = 0; ct < 4; ++ct) acc[ct] = (f32x4){0.f, 0.f, 0.f, 0.f};

    float4 a0, a1, a2, a3, w0, w1, w2, w3;
    a0 = *(const float4*)(xrow + lk16 + 0);
    a1 = *(const float4*)(xrow + lk16 + 4);
    a2 = *(const float4*)(xrow + lk16 + 8);
    a3 = *(const float4*)(xrow + lk16 + 12);
    w0 = *(const float4*)(wrow + lk16 + 0);
    w1 = *(const float4*)(wrow + lk16 + 4);
    w2 = *(const float4*)(wrow + lk16 + 8);
    w3 = *(const float4*)(wrow + lk16 + 12);

    const int NSTEP = IN_FEATS / 64;    // 12
    for (int step = 0; step < NSTEP; ++step) {
        const int buf = step & 1;
        *(short8v*)(AS(buf, lrow) + lk16)     = pack8(a0, a1);
        *(short8v*)(AS(buf, lrow) + lk16 + 8) = pack8(a2, a3);
        *(short8v*)(BS(buf, lrow) + lk16)     = pack8(w0, w1);
        *(short8v*)(BS(buf, lrow) + lk16 + 8) = pack8(w2, w3);
        __syncthreads();

        if (step + 1 < NSTEP) {
            const int k0 = (step + 1) * 64;
            a0 = *(const float4*)(xrow + k0 + lk16 + 0);
            a1 = *(const float4*)(xrow + k0 + lk16 + 4);
            a2 = *(const float4*)(xrow + k0 + lk16 + 8);
            a3 = *(const float4*)(xrow + k0 + lk16 + 12);
            w0 = *(const float4*)(wrow + k0 + lk16 + 0);
            w1 = *(const float4*)(wrow + k0 + lk16 + 4);
            w2 = *(const float4*)(wrow + k0 + lk16 + 8);
            w3 = *(const float4*)(wrow + k0 + lk16 + 12);
        }

        short8v af0 = *(const short8v*)(AS(buf, w * 16 + lr16) + lk);
        short8v af1 = *(const short8v*)(AS(buf, w * 16 + lr16) + lk + 32);
#pragma unroll
        for (int ct = 0; ct < 4; ++ct) {
            short8v bf0 = *(const short8v*)(BS(buf, ct * 16 + lr16) + lk);
            acc[ct] = __builtin_amdgcn_mfma_f32_16x16x32_bf16(af0, bf0, acc[ct], 0, 0, 0);
        }
#pragma unroll
        for (int ct = 0; ct < 4; ++ct) {
            short8v bf1 = *(const short8v*)(BS(buf, ct * 16 + lr16) + lk + 32);
            acc[ct] = __builtin_amdgcn_mfma_f32_16x16x32_bf16(af1, bf1, acc[ct], 0, 0, 0);
        }
    }
#undef AS
#undef BS

    const int rbase = row0 + w * 16 + (l >> 4) * 4;
#pragma unroll
    for (int ct = 0; ct < 4; ++ct) {
        const int ncol = ct * 16 + lr16;
        if (ncol < 32) {
            const int half = ncol >> 4;
            const int c16  = ncol & 15;
            unsigned short* hd = hn1b + (size_t)half * N * 16;
#pragma unroll
            for (int j = 0; j < 4; ++j) {
                const int r = rbase + j;
                if (r < N) hd[(size_t)r * 16 + c16] = f2bf(acc[ct][j]);
            }
        } else {
            const int c = ncol - 32;
            const float bias = b1[c];
#pragma unroll
            for (int j = 0; j < 4; ++j) {
                const int r = rbase + j;
                if (r < N) hs1[(size_t)r * 32 + c] = acc[ct][j] + bias;
            }
        }
    }
}

// ---------------------------------------------------------------------------
// MERGED per-bucket kernel: CSR finalize + agg1 + layer-1 finish + layer-2
// linear. One 1024-thread block per bucket. Bucket-local dependency only
// (no global sync needed): this block scatters edge_src for ITS window,
// barriers, then aggregates ITS 256 nodes — edge_src stays L2-hot on the
// same XCD, and rowstart/cnt come from LDS.
// ---------------------------------------------------------------------------
__global__ __launch_bounds__(1024) void agg1_bucket_kernel(
    const unsigned short* __restrict__ hn1b,   // [2][N][16] halves
    const float* __restrict__ hs1,             // [N,32]
    const unsigned int* __restrict__ packed, const int* __restrict__ bcursor,
    int* __restrict__ rowstart, int* __restrict__ rowcnt,
    int* __restrict__ edge_src,
    const float* __restrict__ Wn2, const float* __restrict__ Ws2,
    const float* __restrict__ b2,
    unsigned short* __restrict__ hn2b, float* __restrict__ hs2,
    int N, int CAP)
{
    __shared__ int cnt[256];
    __shared__ int sdata[256];
    __shared__ int cur[256];
    __shared__ int lstart[256];
    __shared__ float w2[16][33];
    __shared__ float bb[8];
    __shared__ float hsm[128][33];

    const int b = blockIdx.x;
    const int t = threadIdx.x;
    const int base = b * CAP;
    const int endp = min(bcursor[b], base + CAP);

    if (t < 256) {
        w2[t >> 5][t & 31]       = Wn2[t];
        w2[8 + (t >> 5)][t & 31] = Ws2[t];
        if (t < 8) bb[t] = b2[t];
        cnt[t] = 0;
    }
    __syncthreads();

    // ---- finalize: count -> scan -> scatter ----
    for (int i = base + t; i < endp; i += 1024)
        atomicAdd(&cnt[packed[i] >> SRC_BITS], 1);
    __syncthreads();

    if (t < 256) sdata[t] = cnt[t];
    __syncthreads();
    for (int off = 1; off < 256; off <<= 1) {
        const int add = (t < 256 && t >= off) ? sdata[t - off] : 0;
        __syncthreads();
        if (t < 256) sdata[t] += add;
        __syncthreads();
    }
    if (t < 256) {
        const int excl = (t > 0) ? sdata[t - 1] : 0;
        const int n = (b << 8) + t;
        if (n < N) {
            rowstart[n] = base + excl;   // still needed by agg2
            rowcnt[n]   = cnt[t];
        }
        cur[t]    = base + excl;
        lstart[t] = base + excl;
    }
    __syncthreads();

    for (int i = base + t; i < endp; i += 1024) {
        const unsigned int v = packed[i];
        const int pos = atomicAdd(&cur[v >> SRC_BITS], 1);
        edge_src[pos] = (int)(v & SRC_MASK);
    }
    __syncthreads();

    // ---- aggregation + finish + layer-2 GEMV (2 rounds x 128 nodes) ----
    const int g  = t >> 3;       // node slot 0..127
    const int ln = t & 7;        // pair lane 0..7
    const unsigned int* hn1u = (const unsigned int*)hn1b;

    for (int r = 0; r < 2; ++r) {
        const int nl = r * 128 + g;              // local node 0..255
        const int n  = (b << 8) + nl;
        const bool ok = (n < N);
        int rs = 0, degi = 0;
        if (ok) { rs = lstart[nl]; degi = cnt[nl]; }
        const float inv = 1.0f / fmaxf((float)degi, 1.0f);
        const int re = rs + degi;

#pragma unroll
        for (int h = 0; h < 2; ++h) {
            const unsigned int* tab = hn1u + (size_t)h * N * 8;
            float sx = 0.f, sy = 0.f;
            if (ok) {
                int e = rs;
                for (; e + 4 <= re; e += 4) {
                    const int s0 = edge_src[e + 0];
                    const int s1 = edge_src[e + 1];
                    const int s2 = edge_src[e + 2];
                    const int s3 = edge_src[e + 3];
                    const unsigned int v0 = tab[(size_t)s0 * 8 + ln];
                    const unsigned int v1 = tab[(size_t)s1 * 8 + ln];
                    const unsigned int v2 = tab[(size_t)s2 * 8 + ln];
                    const unsigned int v3 = tab[(size_t)s3 * 8 + ln];
                    sx += (bflo(v0) + bflo(v1)) + (bflo(v2) + bflo(v3));
                    sy += (bfhi(v0) + bfhi(v1)) + (bfhi(v2) + bfhi(v3));
                }
                for (; e < re; ++e) {
                    const unsigned int v = tab[(size_t)edge_src[e] * 8 + ln];
                    sx += bflo(v); sy += bfhi(v);
                }
                const int f = h * 16 + 2 * ln;
                const float2 hsv = *(const float2*)(hs1 + (size_t)n * 32 + f);
                hsm[g][f + 0] = fmaxf(hsv.x + sx * inv, 0.0f);
                hsm[g][f + 1] = fmaxf(hsv.y + sy * inv, 0.0f);
            }
        }
        __syncthreads();

        if (ok) {
            const float* hv = hsm[g];
#pragma unroll
            for (int o2 = 0; o2 < 2; ++o2) {
                const int o = o2 * 8 + ln;
                const float* wr = w2[o];
                float acc = 0.0f;
#pragma unroll
                for (int k = 0; k < 32; ++k) acc += wr[k] * hv[k];
                if (o < 8) hn2b[(size_t)n * 8 + o] = f2bf(acc);
                else       hs2[(size_t)n * 8 + (o - 8)] = acc + bb[o - 8];
            }
        }
        __syncthreads();    // hsm reuse next round
    }
}

// ---------------------------------------------------------------------------
// agg2 fused (r12 verbatim): out = hs2 + mean(gather hn2b)
// ---------------------------------------------------------------------------
__global__ __launch_bounds__(256) void agg2_fused_kernel(
    const unsigned short* __restrict__ hn2b, const float* __restrict__ hs2,
    const int* __restrict__ rowstart, const int* __restrict__ rowcnt,
    const int* __restrict__ edge_src,
    float* __restrict__ out, int N)
{
    const int tid  = threadIdx.x;
    const int g    = tid >> 4;
    const int ln   = tid & 15;
    const int slot = ln >> 2;
    const int q    = ln & 3;

    const unsigned int* hn2u = (const unsigned int*)hn2b;

    const int n = blockIdx.x * 16 + g;
    float sx = 0.f, sy = 0.f;
    int degi = 0;
    if (n < N) {
        const int rs = rowstart[n];
        degi = rowcnt[n];
        const int re = rs + degi;
        for (int e = rs + slot; e < re; e += 4) {
            const unsigned int v = hn2u[(size_t)edge_src[e] * 4 + q];
            sx += bflo(v); sy += bfhi(v);
        }
    }
    sx += __shfl_xor(sx, 4, 64);  sy += __shfl_xor(sy, 4, 64);
    sx += __shfl_xor(sx, 8, 64);  sy += __shfl_xor(sy, 8, 64);

    if (n < N && slot == 0) {
        const float inv = 1.0f / fmaxf((float)degi, 1.0f);
        const float2 s = *(const float2*)(hs2 + (size_t)n * 8 + 2 * q);
        float2 o;
        o.x = s.x + sx * inv;
        o.y = s.y + sy * inv;
        *(float2*)(out + (size_t)n * 8 + 2 * q) = o;
    }
}

extern "C" void kernel_launch(void* const* d_in, const int* in_sizes, int n_in,
                              void* d_out, int out_size, void* d_ws, size_t ws_size,
                              hipStream_t stream)
{
    const float* feats = (const float*)d_in[0];
    const int*   src   = (const int*)d_in[1];
    const int*   dst   = (const int*)d_in[2];
    const float* Ws1   = (const float*)d_in[3];
    const float* Wn1   = (const float*)d_in[4];
    const float* b1    = (const float*)d_in[5];
    const float* Ws2   = (const float*)d_in[6];
    const float* Wn2   = (const float*)d_in[7];
    const float* b2    = (const float*)d_in[8];
    float* out = (float*)d_out;

    const int N  = in_sizes[0] / IN_FEATS;   // 100000
    const int E  = in_sizes[1];              // 3200000
    const int NB = (N + 255) >> 8;           // 391
    const int CAP = (int)((((2LL * E) / NB) + 255) & ~255LL);   // 16384

    // Workspace layout (same as round 12)
    char* ws = (char*)d_ws;
    const size_t N32 = (size_t)N * 32;
    const size_t N8  = (size_t)N * 8;
    unsigned short* hn1b = (unsigned short*)ws;            // [2][N][16] bf16
    ws += ((N32 * 2 + 255) / 256) * 256;
    float* hs1 = (float*)ws;                               // [N,32] f32
    ws += ((N32 * 4 + 255) / 256) * 256;
    unsigned short* hn2b = (unsigned short*)ws;            // [N,8] bf16
    ws += ((N8 * 2 + 255) / 256) * 256;
    float* hs2 = (float*)ws;                               // [N,8] f32
    ws += ((N8 * 4 + 255) / 256) * 256;
    int* rowstart = (int*)ws;                              // [N]
    ws += (((size_t)N * 4 + 255) / 256) * 256;
    int* rowcnt = (int*)ws;                                // [N]
    ws += (((size_t)N * 4 + 255) / 256) * 256;
    int* bcursor = (int*)ws;                               // [512]
    ws += 512 * 4;
    unsigned int* packed = (unsigned int*)ws;              // [NB*CAP]
    ws += (((size_t)NB * CAP * 4 + 255) / 256) * 256;
    int* edge_src = (int*)ws;                              // [NB*CAP]

    const int nbPart = (E + PART_CHUNK - 1) / PART_CHUNK;  // 391
    const int nbGemm = (N + 63) / 64;                      // 1563

    // 1) cursor init
    init_cursor_kernel<<<1, 512, 0, stream>>>(bcursor, NB, CAP);

    // 2) FUSED: edge partition || layer-1 GEMM
    gemm_part_kernel<<<nbPart + nbGemm, 256, 0, stream>>>(
        feats, Wn1, Ws1, b1, hn1b, hs1, N,
        src, dst, bcursor, packed, NB, E, CAP, nbPart);

    // 3) MERGED: per-bucket CSR finalize + agg1 + layer-2 linear
    agg1_bucket_kernel<<<NB, 1024, 0, stream>>>(
        hn1b, hs1, packed, bcursor, rowstart, rowcnt, edge_src,
        Wn2, Ws2, b2, hn2b, hs2, N, CAP);

    // 4) layer-2 aggregation + final combine
    agg2_fused_kernel<<<(N + 15) / 16, 256, 0, stream>>>(
        hn2b, hs2, rowstart, rowcnt, edge_src, out, N);
}

// Round 15
// 244.883 us; speedup vs baseline: 2.3558x; 1.0404x over previous
//
#include <hip/hip_runtime.h>
#include <hip/hip_bf16.h>

#define IN_FEATS 768
#define PART_CHUNK 8192
#define SRC_BITS 17
#define SRC_MASK 0x1FFFF

typedef __attribute__((ext_vector_type(8))) short short8v;
typedef __attribute__((ext_vector_type(4))) float f32x4;

__device__ __forceinline__ unsigned short f2bf(float f) {
    union { float f; unsigned int u; } c; c.f = f;
    unsigned int r = (c.u + 0x7FFFu + ((c.u >> 16) & 1u)) >> 16;  // RNE
    return (unsigned short)r;
}
__device__ __forceinline__ float bflo(unsigned int v) {
    union { unsigned int u; float f; } c; c.u = v << 16; return c.f;
}
__device__ __forceinline__ float bfhi(unsigned int v) {
    union { unsigned int u; float f; } c; c.u = v & 0xFFFF0000u; return c.f;
}
__device__ __forceinline__ short8v pack8(float4 p, float4 q) {
    short8v r;
    r[0] = (short)f2bf(p.x); r[1] = (short)f2bf(p.y);
    r[2] = (short)f2bf(p.z); r[3] = (short)f2bf(p.w);
    r[4] = (short)f2bf(q.x); r[5] = (short)f2bf(q.y);
    r[6] = (short)f2bf(q.z); r[7] = (short)f2bf(q.w);
    return r;
}

// ---------------------------------------------------------------------------
// init cursor: bcursor[b] = b*CAP
// ---------------------------------------------------------------------------
__global__ __launch_bounds__(512) void init_cursor_kernel(
    int* __restrict__ bcursor, int NB, int CAP)
{
    const int t = threadIdx.x;
    if (t < NB) bcursor[t] = t * CAP;
}

// ---------------------------------------------------------------------------
// FUSED: blocks [0,nbPart) = edge partition; rest = layer-1 bf16-MFMA GEMM.
// GEMM v4: SINGLE-buffered [64][72] LDS (18.4 KB total -> 8 blocks/CU, was
// 4 at 36.9 KB). r8 counters showed the gemm latency-bound (occ 37%, VALU
// 20%, MfmaUtil 6%) — double the resident blocks to hide HBM latency.
// Cost: 2 barriers/step instead of 1.
// ---------------------------------------------------------------------------
__global__ __launch_bounds__(256) void gemm_part_kernel(
    const float* __restrict__ x,
    const float* __restrict__ Wn,
    const float* __restrict__ Ws,
    const float* __restrict__ b1,
    unsigned short* __restrict__ hn1b,   // [2][N][16] bf16 halves
    float* __restrict__ hs1,             // [N,32]
    int N,
    const int* __restrict__ src, const int* __restrict__ dst,
    int* __restrict__ bcursor, unsigned int* __restrict__ packed,
    int NB, int E, int CAP, int nbPart)
{
    __shared__ __align__(16) unsigned char smem[18432];
    const int tid = threadIdx.x;

    if ((int)blockIdx.x < nbPart) {
        // ================= partition role (r12 verbatim) =================
        int* hcnt  = (int*)smem;         // [512]
        int* hbase = hcnt + 512;         // [512]

        for (int i = tid; i < NB; i += 256) hcnt[i] = 0;
        __syncthreads();

        const int start = blockIdx.x * PART_CHUNK;
        const int end   = min(start + PART_CHUNK, E);
        const int vend  = start + ((end - start) & ~3);

        for (int i = start + tid * 4; i + 3 < end; i += 1024) {
            const int4 d4 = *(const int4*)&dst[i];
            atomicAdd(&hcnt[d4.x >> 8], 1);
            atomicAdd(&hcnt[d4.y >> 8], 1);
            atomicAdd(&hcnt[d4.z >> 8], 1);
            atomicAdd(&hcnt[d4.w >> 8], 1);
        }
        for (int i = vend + tid; i < end; i += 256)
            atomicAdd(&hcnt[dst[i] >> 8], 1);
        __syncthreads();

        for (int i = tid; i < NB; i += 256) {
            const int c = hcnt[i];
            hbase[i] = c ? atomicAdd(&bcursor[i], c) : 0;
            hcnt[i] = 0;
        }
        __syncthreads();

        for (int i = start + tid * 4; i + 3 < end; i += 1024) {
            const int4 d4 = *(const int4*)&dst[i];
            const int4 s4 = *(const int4*)&src[i];
            {
                const int b = d4.x >> 8;
                const int p = hbase[b] + atomicAdd(&hcnt[b], 1);
                if (p < (b + 1) * CAP) packed[p] = ((unsigned int)(d4.x & 255) << SRC_BITS) | (unsigned int)s4.x;
            }
            {
                const int b = d4.y >> 8;
                const int p = hbase[b] + atomicAdd(&hcnt[b], 1);
                if (p < (b + 1) * CAP) packed[p] = ((unsigned int)(d4.y & 255) << SRC_BITS) | (unsigned int)s4.y;
            }
            {
                const int b = d4.z >> 8;
                const int p = hbase[b] + atomicAdd(&hcnt[b], 1);
                if (p < (b + 1) * CAP) packed[p] = ((unsigned int)(d4.z & 255) << SRC_BITS) | (unsigned int)s4.z;
            }
            {
                const int b = d4.w >> 8;
                const int p = hbase[b] + atomicAdd(&hcnt[b], 1);
                if (p < (b + 1) * CAP) packed[p] = ((unsigned int)(d4.w & 255) << SRC_BITS) | (unsigned int)s4.w;
            }
        }
        for (int i = vend + tid; i < end; i += 256) {
            const int d = dst[i];
            const int b = d >> 8;
            const int p = hbase[b] + atomicAdd(&hcnt[b], 1);
            if (p < (b + 1) * CAP) packed[p] = ((unsigned int)(d & 255) << SRC_BITS) | (unsigned int)src[i];
        }
        return;
    }

    // ====== gemm role v4: single-buffer [64][72], BK=64, 2 barriers/step ===
    unsigned short* AsB = (unsigned short*)smem;          // [64][72]
    unsigned short* BsB = AsB + 64 * 72;                  // [64][72]

    const int lrow = tid >> 2;
    const int lk16 = (tid & 3) * 16;
    const int row0 = ((int)blockIdx.x - nbPart) * 64;

    const int  grow   = row0 + lrow;
    const bool rvalid = (grow < N);
    const float* xrow = x + (size_t)(rvalid ? grow : (N - 1)) * IN_FEATS;
    const float* wrow = (lrow < 32) ? (Wn + (size_t)lrow * IN_FEATS)
                                    : (Ws + (size_t)(lrow - 32) * IN_FEATS);

    const int w    = tid >> 6;
    const int l    = tid & 63;
    const int lr16 = l & 15;
    const int lk   = (l >> 4) * 8;

    f32x4 acc[4];
#pragma unroll
    for (int ct = 0; ct < 4; ++ct) acc[ct] = (f32x4){0.f, 0.f, 0.f, 0.f};

    float4 a0, a1, a2, a3, w0, w1, w2, w3;
    a0 = *(const float4*)(xrow + lk16 + 0);
    a1 = *(const float4*)(xrow + lk16 + 4);
    a2 = *(const float4*)(xrow + lk16 + 8);
    a3 = *(const float4*)(xrow + lk16 + 12);
    w0 = *(const float4*)(wrow + lk16 + 0);
    w1 = *(const float4*)(wrow + lk16 + 4);
    w2 = *(const float4*)(wrow + lk16 + 8);
    w3 = *(const float4*)(wrow + lk16 + 12);

    const int NSTEP = IN_FEATS / 64;    // 12
    for (int step = 0; step < NSTEP; ++step) {
        unsigned short* as = AsB + lrow * 72;
        unsigned short* bs = BsB + lrow * 72;
        *(short8v*)(as + lk16)     = pack8(a0, a1);
        *(short8v*)(as + lk16 + 8) = pack8(a2, a3);
        *(short8v*)(bs + lk16)     = pack8(w0, w1);
        *(short8v*)(bs + lk16 + 8) = pack8(w2, w3);
        __syncthreads();

        if (step + 1 < NSTEP) {
            const int k0 = (step + 1) * 64;
            a0 = *(const float4*)(xrow + k0 + lk16 + 0);
            a1 = *(const float4*)(xrow + k0 + lk16 + 4);
            a2 = *(const float4*)(xrow + k0 + lk16 + 8);
            a3 = *(const float4*)(xrow + k0 + lk16 + 12);
            w0 = *(const float4*)(wrow + k0 + lk16 + 0);
            w1 = *(const float4*)(wrow + k0 + lk16 + 4);
            w2 = *(const float4*)(wrow + k0 + lk16 + 8);
            w3 = *(const float4*)(wrow + k0 + lk16 + 12);
        }

        const unsigned short* ar = AsB + (w * 16 + lr16) * 72;
        short8v af0 = *(const short8v*)(ar + lk);
        short8v af1 = *(const short8v*)(ar + lk + 32);
#pragma unroll
        for (int ct = 0; ct < 4; ++ct) {
            const unsigned short* br = BsB + (ct * 16 + lr16) * 72;
            short8v bf0 = *(const short8v*)(br + lk);
            acc[ct] = __builtin_amdgcn_mfma_f32_16x16x32_bf16(af0, bf0, acc[ct], 0, 0, 0);
        }
#pragma unroll
        for (int ct = 0; ct < 4; ++ct) {
            const unsigned short* br = BsB + (ct * 16 + lr16) * 72;
            short8v bf1 = *(const short8v*)(br + lk + 32);
            acc[ct] = __builtin_amdgcn_mfma_f32_16x16x32_bf16(af1, bf1, acc[ct], 0, 0, 0);
        }
        __syncthreads();    // single buffer: drain reads before next stage
    }

    const int rbase = row0 + w * 16 + (l >> 4) * 4;
#pragma unroll
    for (int ct = 0; ct < 4; ++ct) {
        const int ncol = ct * 16 + lr16;
        if (ncol < 32) {
            const int half = ncol >> 4;
            const int c16  = ncol & 15;
            unsigned short* hd = hn1b + (size_t)half * N * 16;
#pragma unroll
            for (int j = 0; j < 4; ++j) {
                const int r = rbase + j;
                if (r < N) hd[(size_t)r * 16 + c16] = f2bf(acc[ct][j]);
            }
        } else {
            const int c = ncol - 32;
            const float bias = b1[c];
#pragma unroll
            for (int j = 0; j < 4; ++j) {
                const int r = rbase + j;
                if (r < N) hs1[(size_t)r * 32 + c] = acc[ct][j] + bias;
            }
        }
    }
}

// ---------------------------------------------------------------------------
// Per-bucket CSR finalize (r12 verbatim).
// ---------------------------------------------------------------------------
__global__ __launch_bounds__(1024) void csr_finalize_kernel(
    const unsigned int* __restrict__ packed, const int* __restrict__ bcursor,
    int* __restrict__ rowstart, int* __restrict__ rowcnt,
    int* __restrict__ edge_src, int N, int CAP)
{
    __shared__ int cnt[256];
    __shared__ int sdata[256];
    __shared__ int cur[256];
    const int b = blockIdx.x;
    const int t = threadIdx.x;
    const int base = b * CAP;
    const int endp = min(bcursor[b], base + CAP);

    if (t < 256) cnt[t] = 0;
    __syncthreads();
    for (int i = base + t; i < endp; i += 1024)
        atomicAdd(&cnt[packed[i] >> SRC_BITS], 1);
    __syncthreads();

    if (t < 256) sdata[t] = cnt[t];
    __syncthreads();
    for (int off = 1; off < 256; off <<= 1) {
        const int add = (t < 256 && t >= off) ? sdata[t - off] : 0;
        __syncthreads();
        if (t < 256) sdata[t] += add;
        __syncthreads();
    }
    if (t < 256) {
        const int excl = (t > 0) ? sdata[t - 1] : 0;
        const int n = (b << 8) + t;
        if (n < N) {
            rowstart[n] = base + excl;
            rowcnt[n]   = cnt[t];
        }
        cur[t] = base + excl;
    }
    __syncthreads();

    for (int i = base + t; i < endp; i += 1024) {
        const unsigned int v = packed[i];
        const int pos = atomicAdd(&cur[v >> SRC_BITS], 1);
        edge_src[pos] = (int)(v & SRC_MASK);
    }
}

// ---------------------------------------------------------------------------
// agg1 fused (r12 verbatim): two L2-resident half passes, 32 nodes/block.
// ---------------------------------------------------------------------------
__global__ __launch_bounds__(256) void agg1_fused_kernel(
    const unsigned short* __restrict__ hn1b,   // [2][N][16] halves
    const float* __restrict__ hs1,             // [N,32]
    const int* __restrict__ rowstart, const int* __restrict__ rowcnt,
    const int* __restrict__ edge_src,
    const float* __restrict__ Wn2, const float* __restrict__ Ws2,
    const float* __restrict__ b2,
    unsigned short* __restrict__ hn2b, float* __restrict__ hs2, int N)
{
    __shared__ float w2[16][33];
    __shared__ float bb[8];
    __shared__ float hsm[32][33];

    const int tid = threadIdx.x;
    const int g   = tid >> 3;      // node slot 0..31
    const int ln  = tid & 7;       // pair lane 0..7

    w2[tid >> 5][tid & 31]       = Wn2[tid];
    w2[8 + (tid >> 5)][tid & 31] = Ws2[tid];
    if (tid < 8) bb[tid] = b2[tid];

    const int n = blockIdx.x * 32 + g;
    int rs = 0, degi = 0;
    if (n < N) { rs = rowstart[n]; degi = rowcnt[n]; }
    const float inv = 1.0f / fmaxf((float)degi, 1.0f);
    const int re = rs + degi;

#pragma unroll
    for (int h = 0; h < 2; ++h) {
        const unsigned int* tab = (const unsigned int*)hn1b + (size_t)h * N * 8;
        float sx = 0.f, sy = 0.f;
        if (n < N) {
            int e = rs;
            for (; e + 4 <= re; e += 4) {
                const int s0 = edge_src[e + 0];
                const int s1 = edge_src[e + 1];
                const int s2 = edge_src[e + 2];
                const int s3 = edge_src[e + 3];
                const unsigned int v0 = tab[(size_t)s0 * 8 + ln];
                const unsigned int v1 = tab[(size_t)s1 * 8 + ln];
                const unsigned int v2 = tab[(size_t)s2 * 8 + ln];
                const unsigned int v3 = tab[(size_t)s3 * 8 + ln];
                sx += (bflo(v0) + bflo(v1)) + (bflo(v2) + bflo(v3));
                sy += (bfhi(v0) + bfhi(v1)) + (bfhi(v2) + bfhi(v3));
            }
            for (; e < re; ++e) {
                const unsigned int v = tab[(size_t)edge_src[e] * 8 + ln];
                sx += bflo(v); sy += bfhi(v);
            }
            const int f = h * 16 + 2 * ln;
            const float2 hsv = *(const float2*)(hs1 + (size_t)n * 32 + f);
            hsm[g][f + 0] = fmaxf(hsv.x + sx * inv, 0.0f);
            hsm[g][f + 1] = fmaxf(hsv.y + sy * inv, 0.0f);
        }
    }
    __syncthreads();

    if (n < N) {
        const float* hv = hsm[g];
#pragma unroll
        for (int o2 = 0; o2 < 2; ++o2) {
            const int o = o2 * 8 + ln;
            const float* wr = w2[o];
            float acc = 0.0f;
#pragma unroll
            for (int k = 0; k < 32; ++k) acc += wr[k] * hv[k];
            if (o < 8) hn2b[(size_t)n * 8 + o] = f2bf(acc);
            else       hs2[(size_t)n * 8 + (o - 8)] = acc + bb[o - 8];
        }
    }
}

// ---------------------------------------------------------------------------
// agg2 fused (r12 verbatim): out = hs2 + mean(gather hn2b)
// ---------------------------------------------------------------------------
__global__ __launch_bounds__(256) void agg2_fused_kernel(
    const unsigned short* __restrict__ hn2b, const float* __restrict__ hs2,
    const int* __restrict__ rowstart, const int* __restrict__ rowcnt,
    const int* __restrict__ edge_src,
    float* __restrict__ out, int N)
{
    const int tid  = threadIdx.x;
    const int g    = tid >> 4;
    const int ln   = tid & 15;
    const int slot = ln >> 2;
    const int q    = ln & 3;

    const unsigned int* hn2u = (const unsigned int*)hn2b;

    const int n = blockIdx.x * 16 + g;
    float sx = 0.f, sy = 0.f;
    int degi = 0;
    if (n < N) {
        const int rs = rowstart[n];
        degi = rowcnt[n];
        const int re = rs + degi;
        for (int e = rs + slot; e < re; e += 4) {
            const unsigned int v = hn2u[(size_t)edge_src[e] * 4 + q];
            sx += bflo(v); sy += bfhi(v);
        }
    }
    sx += __shfl_xor(sx, 4, 64);  sy += __shfl_xor(sy, 4, 64);
    sx += __shfl_xor(sx, 8, 64);  sy += __shfl_xor(sy, 8, 64);

    if (n < N && slot == 0) {
        const float inv = 1.0f / fmaxf((float)degi, 1.0f);
        const float2 s = *(const float2*)(hs2 + (size_t)n * 8 + 2 * q);
        float2 o;
        o.x = s.x + sx * inv;
        o.y = s.y + sy * inv;
        *(float2*)(out + (size_t)n * 8 + 2 * q) = o;
    }
}

extern "C" void kernel_launch(void* const* d_in, const int* in_sizes, int n_in,
                              void* d_out, int out_size, void* d_ws, size_t ws_size,
                              hipStream_t stream)
{
    const float* feats = (const float*)d_in[0];
    const int*   src   = (const int*)d_in[1];
    const int*   dst   = (const int*)d_in[2];
    const float* Ws1   = (const float*)d_in[3];
    const float* Wn1   = (const float*)d_in[4];
    const float* b1    = (const float*)d_in[5];
    const float* Ws2   = (const float*)d_in[6];
    const float* Wn2   = (const float*)d_in[7];
    const float* b2    = (const float*)d_in[8];
    float* out = (float*)d_out;

    const int N  = in_sizes[0] / IN_FEATS;   // 100000
    const int E  = in_sizes[1];              // 3200000
    const int NB = (N + 255) >> 8;           // 391
    const int CAP = (int)((((2LL * E) / NB) + 255) & ~255LL);   // 16384

    // Workspace layout (r12 verbatim)
    char* ws = (char*)d_ws;
    const size_t N32 = (size_t)N * 32;
    const size_t N8  = (size_t)N * 8;
    unsigned short* hn1b = (unsigned short*)ws;            // [2][N][16] bf16
    ws += ((N32 * 2 + 255) / 256) * 256;
    float* hs1 = (float*)ws;                               // [N,32] f32
    ws += ((N32 * 4 + 255) / 256) * 256;
    unsigned short* hn2b = (unsigned short*)ws;            // [N,8] bf16
    ws += ((N8 * 2 + 255) / 256) * 256;
    float* hs2 = (float*)ws;                               // [N,8] f32
    ws += ((N8 * 4 + 255) / 256) * 256;
    int* rowstart = (int*)ws;                              // [N]
    ws += (((size_t)N * 4 + 255) / 256) * 256;
    int* rowcnt = (int*)ws;                                // [N]
    ws += (((size_t)N * 4 + 255) / 256) * 256;
    int* bcursor = (int*)ws;                               // [512]
    ws += 512 * 4;
    unsigned int* packed = (unsigned int*)ws;              // [NB*CAP]
    ws += (((size_t)NB * CAP * 4 + 255) / 256) * 256;
    int* edge_src = (int*)ws;                              // [NB*CAP]

    const int nbPart = (E + PART_CHUNK - 1) / PART_CHUNK;  // 391
    const int nbGemm = (N + 63) / 64;                      // 1563

    // 1) cursor init
    init_cursor_kernel<<<1, 512, 0, stream>>>(bcursor, NB, CAP);

    // 2) FUSED: edge partition || layer-1 GEMM (single-buffered LDS, 8 blk/CU)
    gemm_part_kernel<<<nbPart + nbGemm, 256, 0, stream>>>(
        feats, Wn1, Ws1, b1, hn1b, hs1, N,
        src, dst, bcursor, packed, NB, E, CAP, nbPart);

    // 3) per-bucket CSR finalize
    csr_finalize_kernel<<<NB, 1024, 0, stream>>>(packed, bcursor, rowstart,
                                                 rowcnt, edge_src, N, CAP);

    // 4) layer-1 aggregation (two L2-resident half passes) + layer-2 linear
    agg1_fused_kernel<<<(N + 31) / 32, 256, 0, stream>>>(
        hn1b, hs1, rowstart, rowcnt, edge_src, Wn2, Ws2, b2, hn2b, hs2, N);

    // 5) layer-2 aggregation + final combine
    agg2_fused_kernel<<<(N + 15) / 16, 256, 0, stream>>>(
        hn2b, hs2, rowstart, rowcnt, edge_src, out, N);
}

// Round 16
// 243.335 us; speedup vs baseline: 2.3708x; 1.0064x over previous
//
#include <hip/hip_runtime.h>
#include <hip/hip_bf16.h>

#define IN_FEATS 768
#define PART_CHUNK 8192
#define SRC_BITS 17
#define SRC_MASK 0x1FFFF
#define CELL 56          // slots per (chunk,bucket) cell: mean 21 + 7.6 sigma
#define ECAP 10240       // edge_src per-bucket capacity: mean 8184 + 22 sigma

typedef __attribute__((ext_vector_type(8))) short short8v;
typedef __attribute__((ext_vector_type(4))) float f32x4;

__device__ __forceinline__ unsigned short f2bf(float f) {
    union { float f; unsigned int u; } c; c.f = f;
    unsigned int r = (c.u + 0x7FFFu + ((c.u >> 16) & 1u)) >> 16;  // RNE
    return (unsigned short)r;
}
__device__ __forceinline__ float bflo(unsigned int v) {
    union { unsigned int u; float f; } c; c.u = v << 16; return c.f;
}
__device__ __forceinline__ float bfhi(unsigned int v) {
    union { unsigned int u; float f; } c; c.u = v & 0xFFFF0000u; return c.f;
}
__device__ __forceinline__ short8v pack8(float4 p, float4 q) {
    short8v r;
    r[0] = (short)f2bf(p.x); r[1] = (short)f2bf(p.y);
    r[2] = (short)f2bf(p.z); r[3] = (short)f2bf(p.w);
    r[4] = (short)f2bf(q.x); r[5] = (short)f2bf(q.y);
    r[6] = (short)f2bf(q.z); r[7] = (short)f2bf(q.w);
    return r;
}

// ---------------------------------------------------------------------------
// FUSED: blocks [0,nbPart) = CURSOR-FREE edge partition; rest = layer-1 GEMM
// (r12-v2 verbatim). Partition chunk c writes bucket-b edges into the static
// cell packed[(b*nbPart+c)*CELL ..] using only block-local LDS counters and
// records counts in cntm[c*512+b] — no global cursors, no init launch.
// ---------------------------------------------------------------------------
__global__ __launch_bounds__(256) void gemm_part_kernel(
    const float* __restrict__ x,
    const float* __restrict__ Wn,
    const float* __restrict__ Ws,
    const float* __restrict__ b1,
    unsigned short* __restrict__ hn1b,   // [2][N][16] bf16 halves
    float* __restrict__ hs1,             // [N,32]
    int N,
    const int* __restrict__ src, const int* __restrict__ dst,
    unsigned int* __restrict__ packed,   // [NB*nbPart*CELL]
    int* __restrict__ cntm,              // [nbPart*512]
    int NB, int E, int nbPart)
{
    __shared__ __align__(16) unsigned char smem[36864];
    const int tid = threadIdx.x;

    if ((int)blockIdx.x < nbPart) {
        // ================= partition role (cursor-free) =================
        int* hcnt = (int*)smem;          // [512]
        const int c = blockIdx.x;

        for (int i = tid; i < 512; i += 256) hcnt[i] = 0;
        __syncthreads();

        const int start = c * PART_CHUNK;
        const int end   = min(start + PART_CHUNK, E);
        const int vend  = start + ((end - start) & ~3);

        for (int i = start + tid * 4; i + 3 < end; i += 1024) {
            const int4 d4 = *(const int4*)&dst[i];
            atomicAdd(&hcnt[d4.x >> 8], 1);
            atomicAdd(&hcnt[d4.y >> 8], 1);
            atomicAdd(&hcnt[d4.z >> 8], 1);
            atomicAdd(&hcnt[d4.w >> 8], 1);
        }
        for (int i = vend + tid; i < end; i += 256)
            atomicAdd(&hcnt[dst[i] >> 8], 1);
        __syncthreads();

        for (int i = tid; i < NB; i += 256) {
            cntm[c * 512 + i] = min(hcnt[i], CELL);
            hcnt[i] = 0;     // reuse as local cell cursor
        }
        __syncthreads();

        for (int i = start + tid * 4; i + 3 < end; i += 1024) {
            const int4 d4 = *(const int4*)&dst[i];
            const int4 s4 = *(const int4*)&src[i];
            {
                const int b = d4.x >> 8;
                const int j = atomicAdd(&hcnt[b], 1);
                if (j < CELL) packed[((size_t)b * nbPart + c) * CELL + j] =
                    ((unsigned int)(d4.x & 255) << SRC_BITS) | (unsigned int)s4.x;
            }
            {
                const int b = d4.y >> 8;
                const int j = atomicAdd(&hcnt[b], 1);
                if (j < CELL) packed[((size_t)b * nbPart + c) * CELL + j] =
                    ((unsigned int)(d4.y & 255) << SRC_BITS) | (unsigned int)s4.y;
            }
            {
                const int b = d4.z >> 8;
                const int j = atomicAdd(&hcnt[b], 1);
                if (j < CELL) packed[((size_t)b * nbPart + c) * CELL + j] =
                    ((unsigned int)(d4.z & 255) << SRC_BITS) | (unsigned int)s4.z;
            }
            {
                const int b = d4.w >> 8;
                const int j = atomicAdd(&hcnt[b], 1);
                if (j < CELL) packed[((size_t)b * nbPart + c) * CELL + j] =
                    ((unsigned int)(d4.w & 255) << SRC_BITS) | (unsigned int)s4.w;
            }
        }
        for (int i = vend + tid; i < end; i += 256) {
            const int d = dst[i];
            const int b = d >> 8;
            const int j = atomicAdd(&hcnt[b], 1);
            if (j < CELL) packed[((size_t)b * nbPart + c) * CELL + j] =
                ((unsigned int)(d & 255) << SRC_BITS) | (unsigned int)src[i];
        }
        return;
    }

    // ================= gemm role (r12 v2: [2][64][72], 1 barrier/step) =====
    unsigned short* AsB = (unsigned short*)smem;          // [2][64][72]
    unsigned short* BsB = AsB + 2 * 64 * 72;              // [2][64][72]
#define AS(b, r) (AsB + ((b) * 64 + (r)) * 72)
#define BS(b, r) (BsB + ((b) * 64 + (r)) * 72)

    const int lrow = tid >> 2;
    const int lk16 = (tid & 3) * 16;
    const int row0 = ((int)blockIdx.x - nbPart) * 64;

    const int  grow   = row0 + lrow;
    const bool rvalid = (grow < N);
    const float* xrow = x + (size_t)(rvalid ? grow : (N - 1)) * IN_FEATS;
    const float* wrow = (lrow < 32) ? (Wn + (size_t)lrow * IN_FEATS)
                                    : (Ws + (size_t)(lrow - 32) * IN_FEATS);

    const int w    = tid >> 6;
    const int l    = tid & 63;
    const int lr16 = l & 15;
    const int lk   = (l >> 4) * 8;

    f32x4 acc[4];
#pragma unroll
    for (int ct = 0; ct < 4; ++ct) acc[ct] = (f32x4){0.f, 0.f, 0.f, 0.f};

    float4 a0, a1, a2, a3, w0, w1, w2, w3;
    a0 = *(const float4*)(xrow + lk16 + 0);
    a1 = *(const float4*)(xrow + lk16 + 4);
    a2 = *(const float4*)(xrow + lk16 + 8);
    a3 = *(const float4*)(xrow + lk16 + 12);
    w0 = *(const float4*)(wrow + lk16 + 0);
    w1 = *(const float4*)(wrow + lk16 + 4);
    w2 = *(const float4*)(wrow + lk16 + 8);
    w3 = *(const float4*)(wrow + lk16 + 12);

    const int NSTEP = IN_FEATS / 64;    // 12
    for (int step = 0; step < NSTEP; ++step) {
        const int buf = step & 1;
        *(short8v*)(AS(buf, lrow) + lk16)     = pack8(a0, a1);
        *(short8v*)(AS(buf, lrow) + lk16 + 8) = pack8(a2, a3);
        *(short8v*)(BS(buf, lrow) + lk16)     = pack8(w0, w1);
        *(short8v*)(BS(buf, lrow) + lk16 + 8) = pack8(w2, w3);
        __syncthreads();

        if (step + 1 < NSTEP) {
            const int k0 = (step + 1) * 64;
            a0 = *(const float4*)(xrow + k0 + lk16 + 0);
            a1 = *(const float4*)(xrow + k0 + lk16 + 4);
            a2 = *(const float4*)(xrow + k0 + lk16 + 8);
            a3 = *(const float4*)(xrow + k0 + lk16 + 12);
            w0 = *(const float4*)(wrow + k0 + lk16 + 0);
            w1 = *(const float4*)(wrow + k0 + lk16 + 4);
            w2 = *(const float4*)(wrow + k0 + lk16 + 8);
            w3 = *(const float4*)(wrow + k0 + lk16 + 12);
        }

        short8v af0 = *(const short8v*)(AS(buf, w * 16 + lr16) + lk);
        short8v af1 = *(const short8v*)(AS(buf, w * 16 + lr16) + lk + 32);
#pragma unroll
        for (int ct = 0; ct < 4; ++ct) {
            short8v bf0 = *(const short8v*)(BS(buf, ct * 16 + lr16) + lk);
            acc[ct] = __builtin_amdgcn_mfma_f32_16x16x32_bf16(af0, bf0, acc[ct], 0, 0, 0);
        }
#pragma unroll
        for (int ct = 0; ct < 4; ++ct) {
            short8v bf1 = *(const short8v*)(BS(buf, ct * 16 + lr16) + lk + 32);
            acc[ct] = __builtin_amdgcn_mfma_f32_16x16x32_bf16(af1, bf1, acc[ct], 0, 0, 0);
        }
    }
#undef AS
#undef BS

    const int rbase = row0 + w * 16 + (l >> 4) * 4;
#pragma unroll
    for (int ct = 0; ct < 4; ++ct) {
        const int ncol = ct * 16 + lr16;
        if (ncol < 32) {
            const int half = ncol >> 4;
            const int c16  = ncol & 15;
            unsigned short* hd = hn1b + (size_t)half * N * 16;
#pragma unroll
            for (int j = 0; j < 4; ++j) {
                const int r = rbase + j;
                if (r < N) hd[(size_t)r * 16 + c16] = f2bf(acc[ct][j]);
            }
        } else {
            const int c = ncol - 32;
            const float bias = b1[c];
#pragma unroll
            for (int j = 0; j < 4; ++j) {
                const int r = rbase + j;
                if (r < N) hs1[(size_t)r * 32 + c] = acc[ct][j] + bias;
            }
        }
    }
}

// ---------------------------------------------------------------------------
// Per-bucket CSR finalize over the cell layout: scan this bucket's contiguous
// nbPart*CELL slot region (masked by cntm), count per-node, scan, compact
// into edge_src[b*ECAP ..]. rowstart/rowcnt in ECAP coordinates.
// ---------------------------------------------------------------------------
__global__ __launch_bounds__(1024) void csr_finalize_kernel(
    const unsigned int* __restrict__ packed, const int* __restrict__ cntm,
    int* __restrict__ rowstart, int* __restrict__ rowcnt,
    int* __restrict__ edge_src, int N, int NB, int nbPart)
{
    __shared__ int cellcnt[512];
    __shared__ int cnt[256];
    __shared__ int sdata[256];
    __shared__ int cur[256];
    const int b = blockIdx.x;
    const int t = threadIdx.x;
    const int S = nbPart * CELL;                 // slots per bucket region
    const size_t base_in = (size_t)b * S;

    for (int c = t; c < nbPart; c += 1024) cellcnt[c] = cntm[c * 512 + b];
    if (t < 256) cnt[t] = 0;
    __syncthreads();

    // count phase (masked slot scan)
    for (int i = t; i < S; i += 1024) {
        const int c = i / CELL;
        const int j = i - c * CELL;
        if (j < cellcnt[c])
            atomicAdd(&cnt[packed[base_in + i] >> SRC_BITS], 1);
    }
    __syncthreads();

    if (t < 256) sdata[t] = cnt[t];
    __syncthreads();
    for (int off = 1; off < 256; off <<= 1) {
        const int add = (t < 256 && t >= off) ? sdata[t - off] : 0;
        __syncthreads();
        if (t < 256) sdata[t] += add;
        __syncthreads();
    }
    if (t < 256) {
        const int excl = (t > 0) ? sdata[t - 1] : 0;
        const int n = (b << 8) + t;
        if (n < N) {
            rowstart[n] = b * ECAP + excl;
            rowcnt[n]   = cnt[t];
        }
        cur[t] = b * ECAP + excl;
    }
    __syncthreads();

    // scatter phase (same masked scan)
    for (int i = t; i < S; i += 1024) {
        const int c = i / CELL;
        const int j = i - c * CELL;
        if (j < cellcnt[c]) {
            const unsigned int v = packed[base_in + i];
            const int pos = atomicAdd(&cur[v >> SRC_BITS], 1);
            edge_src[pos] = (int)(v & SRC_MASK);
        }
    }
}

// ---------------------------------------------------------------------------
// agg1 fused (r12 verbatim): two L2-resident half passes, 32 nodes/block.
// ---------------------------------------------------------------------------
__global__ __launch_bounds__(256) void agg1_fused_kernel(
    const unsigned short* __restrict__ hn1b,   // [2][N][16] halves
    const float* __restrict__ hs1,             // [N,32]
    const int* __restrict__ rowstart, const int* __restrict__ rowcnt,
    const int* __restrict__ edge_src,
    const float* __restrict__ Wn2, const float* __restrict__ Ws2,
    const float* __restrict__ b2,
    unsigned short* __restrict__ hn2b, float* __restrict__ hs2, int N)
{
    __shared__ float w2[16][33];
    __shared__ float bb[8];
    __shared__ float hsm[32][33];

    const int tid = threadIdx.x;
    const int g   = tid >> 3;      // node slot 0..31
    const int ln  = tid & 7;       // pair lane 0..7

    w2[tid >> 5][tid & 31]       = Wn2[tid];
    w2[8 + (tid >> 5)][tid & 31] = Ws2[tid];
    if (tid < 8) bb[tid] = b2[tid];

    const int n = blockIdx.x * 32 + g;
    int rs = 0, degi = 0;
    if (n < N) { rs = rowstart[n]; degi = rowcnt[n]; }
    const float inv = 1.0f / fmaxf((float)degi, 1.0f);
    const int re = rs + degi;

#pragma unroll
    for (int h = 0; h < 2; ++h) {
        const unsigned int* tab = (const unsigned int*)hn1b + (size_t)h * N * 8;
        float sx = 0.f, sy = 0.f;
        if (n < N) {
            int e = rs;
            for (; e + 4 <= re; e += 4) {
                const int s0 = edge_src[e + 0];
                const int s1 = edge_src[e + 1];
                const int s2 = edge_src[e + 2];
                const int s3 = edge_src[e + 3];
                const unsigned int v0 = tab[(size_t)s0 * 8 + ln];
                const unsigned int v1 = tab[(size_t)s1 * 8 + ln];
                const unsigned int v2 = tab[(size_t)s2 * 8 + ln];
                const unsigned int v3 = tab[(size_t)s3 * 8 + ln];
                sx += (bflo(v0) + bflo(v1)) + (bflo(v2) + bflo(v3));
                sy += (bfhi(v0) + bfhi(v1)) + (bfhi(v2) + bfhi(v3));
            }
            for (; e < re; ++e) {
                const unsigned int v = tab[(size_t)edge_src[e] * 8 + ln];
                sx += bflo(v); sy += bfhi(v);
            }
            const int f = h * 16 + 2 * ln;
            const float2 hsv = *(const float2*)(hs1 + (size_t)n * 32 + f);
            hsm[g][f + 0] = fmaxf(hsv.x + sx * inv, 0.0f);
            hsm[g][f + 1] = fmaxf(hsv.y + sy * inv, 0.0f);
        }
    }
    __syncthreads();

    if (n < N) {
        const float* hv = hsm[g];
#pragma unroll
        for (int o2 = 0; o2 < 2; ++o2) {
            const int o = o2 * 8 + ln;
            const float* wr = w2[o];
            float acc = 0.0f;
#pragma unroll
            for (int k = 0; k < 32; ++k) acc += wr[k] * hv[k];
            if (o < 8) hn2b[(size_t)n * 8 + o] = f2bf(acc);
            else       hs2[(size_t)n * 8 + (o - 8)] = acc + bb[o - 8];
        }
    }
}

// ---------------------------------------------------------------------------
// agg2 fused (r12 verbatim): out = hs2 + mean(gather hn2b)
// ---------------------------------------------------------------------------
__global__ __launch_bounds__(256) void agg2_fused_kernel(
    const unsigned short* __restrict__ hn2b, const float* __restrict__ hs2,
    const int* __restrict__ rowstart, const int* __restrict__ rowcnt,
    const int* __restrict__ edge_src,
    float* __restrict__ out, int N)
{
    const int tid  = threadIdx.x;
    const int g    = tid >> 4;
    const int ln   = tid & 15;
    const int slot = ln >> 2;
    const int q    = ln & 3;

    const unsigned int* hn2u = (const unsigned int*)hn2b;

    const int n = blockIdx.x * 16 + g;
    float sx = 0.f, sy = 0.f;
    int degi = 0;
    if (n < N) {
        const int rs = rowstart[n];
        degi = rowcnt[n];
        const int re = rs + degi;
        for (int e = rs + slot; e < re; e += 4) {
            const unsigned int v = hn2u[(size_t)edge_src[e] * 4 + q];
            sx += bflo(v); sy += bfhi(v);
        }
    }
    sx += __shfl_xor(sx, 4, 64);  sy += __shfl_xor(sy, 4, 64);
    sx += __shfl_xor(sx, 8, 64);  sy += __shfl_xor(sy, 8, 64);

    if (n < N && slot == 0) {
        const float inv = 1.0f / fmaxf((float)degi, 1.0f);
        const float2 s = *(const float2*)(hs2 + (size_t)n * 8 + 2 * q);
        float2 o;
        o.x = s.x + sx * inv;
        o.y = s.y + sy * inv;
        *(float2*)(out + (size_t)n * 8 + 2 * q) = o;
    }
}

extern "C" void kernel_launch(void* const* d_in, const int* in_sizes, int n_in,
                              void* d_out, int out_size, void* d_ws, size_t ws_size,
                              hipStream_t stream)
{
    const float* feats = (const float*)d_in[0];
    const int*   src   = (const int*)d_in[1];
    const int*   dst   = (const int*)d_in[2];
    const float* Ws1   = (const float*)d_in[3];
    const float* Wn1   = (const float*)d_in[4];
    const float* b1    = (const float*)d_in[5];
    const float* Ws2   = (const float*)d_in[6];
    const float* Wn2   = (const float*)d_in[7];
    const float* b2    = (const float*)d_in[8];
    float* out = (float*)d_out;

    const int N  = in_sizes[0] / IN_FEATS;   // 100000
    const int E  = in_sizes[1];              // 3200000
    const int NB = (N + 255) >> 8;           // 391
    const int nbPart = (E + PART_CHUNK - 1) / PART_CHUNK;  // 391
    const int nbGemm = (N + 63) / 64;                      // 1563

    // Workspace layout
    char* ws = (char*)d_ws;
    const size_t N32 = (size_t)N * 32;
    const size_t N8  = (size_t)N * 8;
    unsigned short* hn1b = (unsigned short*)ws;            // [2][N][16] bf16
    ws += ((N32 * 2 + 255) / 256) * 256;
    float* hs1 = (float*)ws;                               // [N,32] f32
    ws += ((N32 * 4 + 255) / 256) * 256;
    unsigned short* hn2b = (unsigned short*)ws;            // [N,8] bf16
    ws += ((N8 * 2 + 255) / 256) * 256;
    float* hs2 = (float*)ws;                               // [N,8] f32
    ws += ((N8 * 4 + 255) / 256) * 256;
    int* rowstart = (int*)ws;                              // [N]
    ws += (((size_t)N * 4 + 255) / 256) * 256;
    int* rowcnt = (int*)ws;                                // [N]
    ws += (((size_t)N * 4 + 255) / 256) * 256;
    int* cntm = (int*)ws;                                  // [nbPart*512]
    ws += (((size_t)nbPart * 512 * 4 + 255) / 256) * 256;
    unsigned int* packed = (unsigned int*)ws;              // [NB*nbPart*CELL]
    ws += (((size_t)NB * nbPart * CELL * 4 + 255) / 256) * 256;
    int* edge_src = (int*)ws;                              // [NB*ECAP]

    // 1) FUSED: cursor-free edge partition || layer-1 GEMM
    gemm_part_kernel<<<nbPart + nbGemm, 256, 0, stream>>>(
        feats, Wn1, Ws1, b1, hn1b, hs1, N,
        src, dst, packed, cntm, NB, E, nbPart);

    // 2) per-bucket CSR finalize (cell scan -> compact edge_src)
    csr_finalize_kernel<<<NB, 1024, 0, stream>>>(packed, cntm, rowstart,
                                                 rowcnt, edge_src, N, NB, nbPart);

    // 3) layer-1 aggregation (two L2-resident half passes) + layer-2 linear
    agg1_fused_kernel<<<(N + 31) / 32, 256, 0, stream>>>(
        hn1b, hs1, rowstart, rowcnt, edge_src, Wn2, Ws2, b2, hn2b, hs2, N);

    // 4) layer-2 aggregation + final combine
    agg2_fused_kernel<<<(N + 15) / 16, 256, 0, stream>>>(
        hn2b, hs2, rowstart, rowcnt, edge_src, out, N);
}

// Round 17
// 239.402 us; speedup vs baseline: 2.4098x; 1.0164x over previous
//
#include <hip/hip_runtime.h>
#include <hip/hip_bf16.h>

#define IN_FEATS 768
#define PART_CHUNK 8192
#define SRC_BITS 17
#define SRC_MASK 0x1FFFF

typedef __attribute__((ext_vector_type(8))) short short8v;
typedef __attribute__((ext_vector_type(4))) float f32x4;

__device__ __forceinline__ unsigned short f2bf(float f) {
    union { float f; unsigned int u; } c; c.f = f;
    unsigned int r = (c.u + 0x7FFFu + ((c.u >> 16) & 1u)) >> 16;  // RNE
    return (unsigned short)r;
}
__device__ __forceinline__ float bflo(unsigned int v) {
    union { unsigned int u; float f; } c; c.u = v << 16; return c.f;
}
__device__ __forceinline__ float bfhi(unsigned int v) {
    union { unsigned int u; float f; } c; c.u = v & 0xFFFF0000u; return c.f;
}
__device__ __forceinline__ short8v pack8(float4 p, float4 q) {
    short8v r;
    r[0] = (short)f2bf(p.x); r[1] = (short)f2bf(p.y);
    r[2] = (short)f2bf(p.z); r[3] = (short)f2bf(p.w);
    r[4] = (short)f2bf(q.x); r[5] = (short)f2bf(q.y);
    r[6] = (short)f2bf(q.z); r[7] = (short)f2bf(q.w);
    return r;
}

// ---------------------------------------------------------------------------
// init cursor: bcursor[b] = b*CAP
// ---------------------------------------------------------------------------
__global__ __launch_bounds__(512) void init_cursor_kernel(
    int* __restrict__ bcursor, int NB, int CAP)
{
    const int t = threadIdx.x;
    if (t < NB) bcursor[t] = t * CAP;
}

// ---------------------------------------------------------------------------
// FUSED: blocks [0,nbPart) = edge partition; rest = layer-1 bf16-MFMA GEMM
// (r12 measured-best configuration, restored verbatim).
// ---------------------------------------------------------------------------
__global__ __launch_bounds__(256) void gemm_part_kernel(
    const float* __restrict__ x,
    const float* __restrict__ Wn,
    const float* __restrict__ Ws,
    const float* __restrict__ b1,
    unsigned short* __restrict__ hn1b,   // [2][N][16] bf16 halves
    float* __restrict__ hs1,             // [N,32]
    int N,
    const int* __restrict__ src, const int* __restrict__ dst,
    int* __restrict__ bcursor, unsigned int* __restrict__ packed,
    int NB, int E, int CAP, int nbPart)
{
    __shared__ __align__(16) unsigned char smem[36864];
    const int tid = threadIdx.x;

    if ((int)blockIdx.x < nbPart) {
        // ================= partition role =================
        int* hcnt  = (int*)smem;         // [512]
        int* hbase = hcnt + 512;         // [512]

        for (int i = tid; i < NB; i += 256) hcnt[i] = 0;
        __syncthreads();

        const int start = blockIdx.x * PART_CHUNK;
        const int end   = min(start + PART_CHUNK, E);
        const int vend  = start + ((end - start) & ~3);

        for (int i = start + tid * 4; i + 3 < end; i += 1024) {
            const int4 d4 = *(const int4*)&dst[i];
            atomicAdd(&hcnt[d4.x >> 8], 1);
            atomicAdd(&hcnt[d4.y >> 8], 1);
            atomicAdd(&hcnt[d4.z >> 8], 1);
            atomicAdd(&hcnt[d4.w >> 8], 1);
        }
        for (int i = vend + tid; i < end; i += 256)
            atomicAdd(&hcnt[dst[i] >> 8], 1);
        __syncthreads();

        for (int i = tid; i < NB; i += 256) {
            const int c = hcnt[i];
            hbase[i] = c ? atomicAdd(&bcursor[i], c) : 0;
            hcnt[i] = 0;
        }
        __syncthreads();

        for (int i = start + tid * 4; i + 3 < end; i += 1024) {
            const int4 d4 = *(const int4*)&dst[i];
            const int4 s4 = *(const int4*)&src[i];
            {
                const int b = d4.x >> 8;
                const int p = hbase[b] + atomicAdd(&hcnt[b], 1);
                if (p < (b + 1) * CAP) packed[p] = ((unsigned int)(d4.x & 255) << SRC_BITS) | (unsigned int)s4.x;
            }
            {
                const int b = d4.y >> 8;
                const int p = hbase[b] + atomicAdd(&hcnt[b], 1);
                if (p < (b + 1) * CAP) packed[p] = ((unsigned int)(d4.y & 255) << SRC_BITS) | (unsigned int)s4.y;
            }
            {
                const int b = d4.z >> 8;
                const int p = hbase[b] + atomicAdd(&hcnt[b], 1);
                if (p < (b + 1) * CAP) packed[p] = ((unsigned int)(d4.z & 255) << SRC_BITS) | (unsigned int)s4.z;
            }
            {
                const int b = d4.w >> 8;
                const int p = hbase[b] + atomicAdd(&hcnt[b], 1);
                if (p < (b + 1) * CAP) packed[p] = ((unsigned int)(d4.w & 255) << SRC_BITS) | (unsigned int)s4.w;
            }
        }
        for (int i = vend + tid; i < end; i += 256) {
            const int d = dst[i];
            const int b = d >> 8;
            const int p = hbase[b] + atomicAdd(&hcnt[b], 1);
            if (p < (b + 1) * CAP) packed[p] = ((unsigned int)(d & 255) << SRC_BITS) | (unsigned int)src[i];
        }
        return;
    }

    // ================= gemm role (v2: [2][64][72], one barrier/step) =======
    unsigned short* AsB = (unsigned short*)smem;          // [2][64][72]
    unsigned short* BsB = AsB + 2 * 64 * 72;              // [2][64][72]
#define AS(b, r) (AsB + ((b) * 64 + (r)) * 72)
#define BS(b, r) (BsB + ((b) * 64 + (r)) * 72)

    const int lrow = tid >> 2;
    const int lk16 = (tid & 3) * 16;
    const int row0 = ((int)blockIdx.x - nbPart) * 64;

    const int  grow   = row0 + lrow;
    const bool rvalid = (grow < N);
    const float* xrow = x + (size_t)(rvalid ? grow : (N - 1)) * IN_FEATS;
    const float* wrow = (lrow < 32) ? (Wn + (size_t)lrow * IN_FEATS)
                                    : (Ws + (size_t)(lrow - 32) * IN_FEATS);

    const int w    = tid >> 6;
    const int l    = tid & 63;
    const int lr16 = l & 15;
    const int lk   = (l >> 4) * 8;

    f32x4 acc[4];
#pragma unroll
    for (int ct = 0; ct < 4; ++ct) acc[ct] = (f32x4){0.f, 0.f, 0.f, 0.f};

    float4 a0, a1, a2, a3, w0, w1, w2, w3;
    a0 = *(const float4*)(xrow + lk16 + 0);
    a1 = *(const float4*)(xrow + lk16 + 4);
    a2 = *(const float4*)(xrow + lk16 + 8);
    a3 = *(const float4*)(xrow + lk16 + 12);
    w0 = *(const float4*)(wrow + lk16 + 0);
    w1 = *(const float4*)(wrow + lk16 + 4);
    w2 = *(const float4*)(wrow + lk16 + 8);
    w3 = *(const float4*)(wrow + lk16 + 12);

    const int NSTEP = IN_FEATS / 64;    // 12
    for (int step = 0; step < NSTEP; ++step) {
        const int buf = step & 1;
        *(short8v*)(AS(buf, lrow) + lk16)     = pack8(a0, a1);
        *(short8v*)(AS(buf, lrow) + lk16 + 8) = pack8(a2, a3);
        *(short8v*)(BS(buf, lrow) + lk16)     = pack8(w0, w1);
        *(short8v*)(BS(buf, lrow) + lk16 + 8) = pack8(w2, w3);
        __syncthreads();

        if (step + 1 < NSTEP) {
            const int k0 = (step + 1) * 64;
            a0 = *(const float4*)(xrow + k0 + lk16 + 0);
            a1 = *(const float4*)(xrow + k0 + lk16 + 4);
            a2 = *(const float4*)(xrow + k0 + lk16 + 8);
            a3 = *(const float4*)(xrow + k0 + lk16 + 12);
            w0 = *(const float4*)(wrow + k0 + lk16 + 0);
            w1 = *(const float4*)(wrow + k0 + lk16 + 4);
            w2 = *(const float4*)(wrow + k0 + lk16 + 8);
            w3 = *(const float4*)(wrow + k0 + lk16 + 12);
        }

        short8v af0 = *(const short8v*)(AS(buf, w * 16 + lr16) + lk);
        short8v af1 = *(const short8v*)(AS(buf, w * 16 + lr16) + lk + 32);
#pragma unroll
        for (int ct = 0; ct < 4; ++ct) {
            short8v bf0 = *(const short8v*)(BS(buf, ct * 16 + lr16) + lk);
            acc[ct] = __builtin_amdgcn_mfma_f32_16x16x32_bf16(af0, bf0, acc[ct], 0, 0, 0);
        }
#pragma unroll
        for (int ct = 0; ct < 4; ++ct) {
            short8v bf1 = *(const short8v*)(BS(buf, ct * 16 + lr16) + lk + 32);
            acc[ct] = __builtin_amdgcn_mfma_f32_16x16x32_bf16(af1, bf1, acc[ct], 0, 0, 0);
        }
    }
#undef AS
#undef BS

    const int rbase = row0 + w * 16 + (l >> 4) * 4;
#pragma unroll
    for (int ct = 0; ct < 4; ++ct) {
        const int ncol = ct * 16 + lr16;
        if (ncol < 32) {
            const int half = ncol >> 4;
            const int c16  = ncol & 15;
            unsigned short* hd = hn1b + (size_t)half * N * 16;
#pragma unroll
            for (int j = 0; j < 4; ++j) {
                const int r = rbase + j;
                if (r < N) hd[(size_t)r * 16 + c16] = f2bf(acc[ct][j]);
            }
        } else {
            const int c = ncol - 32;
            const float bias = b1[c];
#pragma unroll
            for (int j = 0; j < 4; ++j) {
                const int r = rbase + j;
                if (r < N) hs1[(size_t)r * 32 + c] = acc[ct][j] + bias;
            }
        }
    }
}

// ---------------------------------------------------------------------------
// Per-bucket CSR finalize (r12 verbatim).
// ---------------------------------------------------------------------------
__global__ __launch_bounds__(1024) void csr_finalize_kernel(
    const unsigned int* __restrict__ packed, const int* __restrict__ bcursor,
    int* __restrict__ rowstart, int* __restrict__ rowcnt,
    int* __restrict__ edge_src, int N, int CAP)
{
    __shared__ int cnt[256];
    __shared__ int sdata[256];
    __shared__ int cur[256];
    const int b = blockIdx.x;
    const int t = threadIdx.x;
    const int base = b * CAP;
    const int endp = min(bcursor[b], base + CAP);

    if (t < 256) cnt[t] = 0;
    __syncthreads();
    for (int i = base + t; i < endp; i += 1024)
        atomicAdd(&cnt[packed[i] >> SRC_BITS], 1);
    __syncthreads();

    if (t < 256) sdata[t] = cnt[t];
    __syncthreads();
    for (int off = 1; off < 256; off <<= 1) {
        const int add = (t < 256 && t >= off) ? sdata[t - off] : 0;
        __syncthreads();
        if (t < 256) sdata[t] += add;
        __syncthreads();
    }
    if (t < 256) {
        const int excl = (t > 0) ? sdata[t - 1] : 0;
        const int n = (b << 8) + t;
        if (n < N) {
            rowstart[n] = base + excl;
            rowcnt[n]   = cnt[t];
        }
        cur[t] = base + excl;
    }
    __syncthreads();

    for (int i = base + t; i < endp; i += 1024) {
        const unsigned int v = packed[i];
        const int pos = atomicAdd(&cur[v >> SRC_BITS], 1);
        edge_src[pos] = (int)(v & SRC_MASK);
    }
}

// ---------------------------------------------------------------------------
// agg1 fused (r12 verbatim): two L2-resident half passes, 32 nodes/block.
// ---------------------------------------------------------------------------
__global__ __launch_bounds__(256) void agg1_fused_kernel(
    const unsigned short* __restrict__ hn1b,   // [2][N][16] halves
    const float* __restrict__ hs1,             // [N,32]
    const int* __restrict__ rowstart, const int* __restrict__ rowcnt,
    const int* __restrict__ edge_src,
    const float* __restrict__ Wn2, const float* __restrict__ Ws2,
    const float* __restrict__ b2,
    unsigned short* __restrict__ hn2b, float* __restrict__ hs2, int N)
{
    __shared__ float w2[16][33];
    __shared__ float bb[8];
    __shared__ float hsm[32][33];

    const int tid = threadIdx.x;
    const int g   = tid >> 3;      // node slot 0..31
    const int ln  = tid & 7;       // pair lane 0..7

    w2[tid >> 5][tid & 31]       = Wn2[tid];
    w2[8 + (tid >> 5)][tid & 31] = Ws2[tid];
    if (tid < 8) bb[tid] = b2[tid];

    const int n = blockIdx.x * 32 + g;
    int rs = 0, degi = 0;
    if (n < N) { rs = rowstart[n]; degi = rowcnt[n]; }
    const float inv = 1.0f / fmaxf((float)degi, 1.0f);
    const int re = rs + degi;

#pragma unroll
    for (int h = 0; h < 2; ++h) {
        const unsigned int* tab = (const unsigned int*)hn1b + (size_t)h * N * 8;
        float sx = 0.f, sy = 0.f;
        if (n < N) {
            int e = rs;
            for (; e + 4 <= re; e += 4) {
                const int s0 = edge_src[e + 0];
                const int s1 = edge_src[e + 1];
                const int s2 = edge_src[e + 2];
                const int s3 = edge_src[e + 3];
                const unsigned int v0 = tab[(size_t)s0 * 8 + ln];
                const unsigned int v1 = tab[(size_t)s1 * 8 + ln];
                const unsigned int v2 = tab[(size_t)s2 * 8 + ln];
                const unsigned int v3 = tab[(size_t)s3 * 8 + ln];
                sx += (bflo(v0) + bflo(v1)) + (bflo(v2) + bflo(v3));
                sy += (bfhi(v0) + bfhi(v1)) + (bfhi(v2) + bfhi(v3));
            }
            for (; e < re; ++e) {
                const unsigned int v = tab[(size_t)edge_src[e] * 8 + ln];
                sx += bflo(v); sy += bfhi(v);
            }
            const int f = h * 16 + 2 * ln;
            const float2 hsv = *(const float2*)(hs1 + (size_t)n * 32 + f);
            hsm[g][f + 0] = fmaxf(hsv.x + sx * inv, 0.0f);
            hsm[g][f + 1] = fmaxf(hsv.y + sy * inv, 0.0f);
        }
    }
    __syncthreads();

    if (n < N) {
        const float* hv = hsm[g];
#pragma unroll
        for (int o2 = 0; o2 < 2; ++o2) {
            const int o = o2 * 8 + ln;
            const float* wr = w2[o];
            float acc = 0.0f;
#pragma unroll
            for (int k = 0; k < 32; ++k) acc += wr[k] * hv[k];
            if (o < 8) hn2b[(size_t)n * 8 + o] = f2bf(acc);
            else       hs2[(size_t)n * 8 + (o - 8)] = acc + bb[o - 8];
        }
    }
}

// ---------------------------------------------------------------------------
// agg2 fused (r12 verbatim): out = hs2 + mean(gather hn2b)
// ---------------------------------------------------------------------------
__global__ __launch_bounds__(256) void agg2_fused_kernel(
    const unsigned short* __restrict__ hn2b, const float* __restrict__ hs2,
    const int* __restrict__ rowstart, const int* __restrict__ rowcnt,
    const int* __restrict__ edge_src,
    float* __restrict__ out, int N)
{
    const int tid  = threadIdx.x;
    const int g    = tid >> 4;
    const int ln   = tid & 15;
    const int slot = ln >> 2;
    const int q    = ln & 3;

    const unsigned int* hn2u = (const unsigned int*)hn2b;

    const int n = blockIdx.x * 16 + g;
    float sx = 0.f, sy = 0.f;
    int degi = 0;
    if (n < N) {
        const int rs = rowstart[n];
        degi = rowcnt[n];
        const int re = rs + degi;
        for (int e = rs + slot; e < re; e += 4) {
            const unsigned int v = hn2u[(size_t)edge_src[e] * 4 + q];
            sx += bflo(v); sy += bfhi(v);
        }
    }
    sx += __shfl_xor(sx, 4, 64);  sy += __shfl_xor(sy, 4, 64);
    sx += __shfl_xor(sx, 8, 64);  sy += __shfl_xor(sy, 8, 64);

    if (n < N && slot == 0) {
        const float inv = 1.0f / fmaxf((float)degi, 1.0f);
        const float2 s = *(const float2*)(hs2 + (size_t)n * 8 + 2 * q);
        float2 o;
        o.x = s.x + sx * inv;
        o.y = s.y + sy * inv;
        *(float2*)(out + (size_t)n * 8 + 2 * q) = o;
    }
}

extern "C" void kernel_launch(void* const* d_in, const int* in_sizes, int n_in,
                              void* d_out, int out_size, void* d_ws, size_t ws_size,
                              hipStream_t stream)
{
    const float* feats = (const float*)d_in[0];
    const int*   src   = (const int*)d_in[1];
    const int*   dst   = (const int*)d_in[2];
    const float* Ws1   = (const float*)d_in[3];
    const float* Wn1   = (const float*)d_in[4];
    const float* b1    = (const float*)d_in[5];
    const float* Ws2   = (const float*)d_in[6];
    const float* Wn2   = (const float*)d_in[7];
    const float* b2    = (const float*)d_in[8];
    float* out = (float*)d_out;

    const int N  = in_sizes[0] / IN_FEATS;   // 100000
    const int E  = in_sizes[1];              // 3200000
    const int NB = (N + 255) >> 8;           // 391
    const int CAP = (int)((((2LL * E) / NB) + 255) & ~255LL);   // 16384

    // Workspace layout (r12 verbatim)
    char* ws = (char*)d_ws;
    const size_t N32 = (size_t)N * 32;
    const size_t N8  = (size_t)N * 8;
    unsigned short* hn1b = (unsigned short*)ws;            // [2][N][16] bf16
    ws += ((N32 * 2 + 255) / 256) * 256;
    float* hs1 = (float*)ws;                               // [N,32] f32
    ws += ((N32 * 4 + 255) / 256) * 256;
    unsigned short* hn2b = (unsigned short*)ws;            // [N,8] bf16
    ws += ((N8 * 2 + 255) / 256) * 256;
    float* hs2 = (float*)ws;                               // [N,8] f32
    ws += ((N8 * 4 + 255) / 256) * 256;
    int* rowstart = (int*)ws;                              // [N]
    ws += (((size_t)N * 4 + 255) / 256) * 256;
    int* rowcnt = (int*)ws;                                // [N]
    ws += (((size_t)N * 4 + 255) / 256) * 256;
    int* bcursor = (int*)ws;                               // [512]
    ws += 512 * 4;
    unsigned int* packed = (unsigned int*)ws;              // [NB*CAP]
    ws += (((size_t)NB * CAP * 4 + 255) / 256) * 256;
    int* edge_src = (int*)ws;                              // [NB*CAP]

    const int nbPart = (E + PART_CHUNK - 1) / PART_CHUNK;  // 391
    const int nbGemm = (N + 63) / 64;                      // 1563

    // 1) cursor init
    init_cursor_kernel<<<1, 512, 0, stream>>>(bcursor, NB, CAP);

    // 2) FUSED: edge partition || layer-1 GEMM
    gemm_part_kernel<<<nbPart + nbGemm, 256, 0, stream>>>(
        feats, Wn1, Ws1, b1, hn1b, hs1, N,
        src, dst, bcursor, packed, NB, E, CAP, nbPart);

    // 3) per-bucket CSR finalize
    csr_finalize_kernel<<<NB, 1024, 0, stream>>>(packed, bcursor, rowstart,
                                                 rowcnt, edge_src, N, CAP);

    // 4) layer-1 aggregation (two L2-resident half passes) + layer-2 linear
    agg1_fused_kernel<<<(N + 31) / 32, 256, 0, stream>>>(
        hn1b, hs1, rowstart, rowcnt, edge_src, Wn2, Ws2, b2, hn2b, hs2, N);

    // 5) layer-2 aggregation + final combine
    agg2_fused_kernel<<<(N + 15) / 16, 256, 0, stream>>>(
        hn2b, hs2, rowstart, rowcnt, edge_src, out, N);
}